// Round 20
// baseline (447.310 us; speedup 1.0000x reference)
//
#include <hip/hip_runtime.h>
#include <hip/hip_bf16.h>
#include <hip/hip_fp16.h>
#include <math.h>

#define HD 4
#define CH 64
#define GHC 256
#define NEG 0.2f
#define CHUNK 4096
#define BCAP 16384

#define WAVE_SYNC() do { __builtin_amdgcn_wave_barrier(); \
                         asm volatile("s_waitcnt lgkmcnt(0)" ::: "memory"); } while (0)

typedef _Float16 f16x8 __attribute__((ext_vector_type(8)));
typedef float f32x4 __attribute__((ext_vector_type(4)));

__device__ __forceinline__ float wsum32(float v){
  #pragma unroll
  for (int o = 16; o > 0; o >>= 1) v += __shfl_xor(v, o);
  return v;
}

// ---------------- CSR build (bucket-based) ----------------
__global__ __launch_bounds__(256)
void bin_stage(const int* __restrict__ ei, int E, int N,
               int* __restrict__ bres, unsigned* __restrict__ pairs)
{
  __shared__ unsigned staged[CHUNK];
  __shared__ unsigned short bkt[CHUNK];
  __shared__ int cnts[256], loff[256], gpos[256];
  const int t = threadIdx.x;
  const int tot = E + N;
  const int cbase = blockIdx.x * CHUNK;
  if (cbase >= tot) return;

  cnts[t] = 0;
  __syncthreads();

  unsigned myp[CHUNK / 256];
  int myb[CHUNK / 256], myr[CHUNK / 256];
  #pragma unroll
  for (int j = 0; j < CHUNK / 256; j++){
    int i = cbase + t + j * 256;
    myb[j] = -1;
    if (i < tot){
      int src, dst;
      if (i < E){ src = ei[i]; dst = ei[E + i]; }
      else { src = dst = i - E; }
      myb[j] = dst >> 8;
      myp[j] = (unsigned)src | ((unsigned)dst << 16);
      myr[j] = atomicAdd(&cnts[myb[j]], 1);
    }
  }
  __syncthreads();

  int v = cnts[t];
  loff[t] = v;
  __syncthreads();
  for (int o = 1; o < 256; o <<= 1){
    int tv = (t >= o) ? loff[t - o] : 0;
    __syncthreads();
    loff[t] += tv;
    __syncthreads();
  }
  int excl = loff[t] - v;
  __syncthreads();
  loff[t] = excl;
  __syncthreads();

  #pragma unroll
  for (int j = 0; j < CHUNK / 256; j++){
    if (myb[j] >= 0){
      int slot = loff[myb[j]] + myr[j];
      staged[slot] = myp[j];
      bkt[slot] = (unsigned short)myb[j];
    }
  }
  if (v > 0) gpos[t] = atomicAdd(&bres[t], v);
  __syncthreads();

  int total = min(CHUNK, tot - cbase);
  for (int i = t; i < total; i += 256){
    int b = bkt[i];
    int addr = b * BCAP + gpos[b] + (i - loff[b]);
    pairs[addr] = staged[i];
  }
}

__global__ __launch_bounds__(256)
void build_csr(const unsigned* __restrict__ pairs, const int* __restrict__ bres,
               int N, int Etot, int* __restrict__ offs, unsigned short* __restrict__ csr,
               int* __restrict__ ghist)
{
  __shared__ int dcnt[256], doff[256], bscan[256];
  const int b = blockIdx.x, t = threadIdx.x;
  int bv = bres[t];
  bscan[t] = bv;
  __syncthreads();
  for (int o = 1; o < 256; o <<= 1){
    int tv = (t >= o) ? bscan[t - o] : 0;
    __syncthreads();
    bscan[t] += tv;
    __syncthreads();
  }
  const int beg = bscan[b] - bres[b];
  const int cnt = bres[b];
  const unsigned* pb = pairs + (size_t)b * BCAP;
  dcnt[t] = 0;
  __syncthreads();
  for (int i = t; i < cnt; i += 256)
    atomicAdd(&dcnt[(pb[i] >> 16) & 255], 1);
  __syncthreads();
  int v = dcnt[t];
  doff[t] = v;
  __syncthreads();
  for (int o = 1; o < 256; o <<= 1){
    int tv = (t >= o) ? doff[t - o] : 0;
    __syncthreads();
    doff[t] += tv;
    __syncthreads();
  }
  int excl = doff[t] - v;
  __syncthreads();
  doff[t] = excl;
  __syncthreads();
  int node = (b << 8) + t;
  if (node < N){
    offs[node] = beg + doff[t];
    atomicAdd(&ghist[min(v, 255)], 1);   // degree histogram for perm sort
  }
  if (b == 0 && t == 0) offs[N] = Etot;
  dcnt[t] = 0;
  __syncthreads();
  for (int i = t; i < cnt; i += 256){
    unsigned pr = pb[i];
    int l = (pr >> 16) & 255;
    int pos = beg + doff[l] + atomicAdd(&dcnt[l], 1);
    csr[pos] = (unsigned short)(pr & 0xFFFF);
  }
}

// counting-sort scatter: perm[] = nodes ordered by (capped) degree.
// Per-node outputs are order-invariant, so within-bin placement order
// (atomic) does not affect results.
__global__ __launch_bounds__(256)
void perm_scatter(const int* __restrict__ offs, const int* __restrict__ ghist,
                  int* __restrict__ gbincnt, int* __restrict__ perm, int N)
{
  __shared__ int sc[256];
  const int t = threadIdx.x;
  int v = ghist[t];
  sc[t] = v;
  __syncthreads();
  for (int o = 1; o < 256; o <<= 1){
    int tv = (t >= o) ? sc[t - o] : 0;
    __syncthreads();
    sc[t] += tv;
    __syncthreads();
  }
  __shared__ int base[256];
  base[t] = sc[t] - v;
  __syncthreads();
  int node = blockIdx.x * 256 + t;
  if (node < N){
    int deg = offs[node + 1] - offs[node];
    int bin = min(deg, 255);
    int pos = base[bin] + atomicAdd(&gbincnt[bin], 1);
    perm[pos] = node;
  }
}

// ---------------- fused-weight precompute + MFMA packing + graph bounds ----------------
__global__ __launch_bounds__(256)
void fuse_all(const float* __restrict__ W1, const float* __restrict__ a1s,
              const float* __restrict__ a1d, const float* __restrict__ b1,
              const float* __restrict__ h1w, const float* __restrict__ h1b,
              const float* __restrict__ W2, const float* __restrict__ a2s,
              const float* __restrict__ a2d, const float* __restrict__ b2,
              const float* __restrict__ h2w, const float* __restrict__ h2b,
              const float* __restrict__ W3, const float* __restrict__ a3s,
              const float* __restrict__ a3d, const float* __restrict__ b3,
              const float* __restrict__ h3w, const float* __restrict__ h3b,
              __half* __restrict__ Wpk1, float* __restrict__ Psd1, float* __restrict__ cb1,
              __half* __restrict__ Wpk2, __half* __restrict__ Ppk2, float* __restrict__ cb2,
              float* __restrict__ Wcp3, __half* __restrict__ Ppk3, float* __restrict__ cb3,
              const int* __restrict__ batch, int N, int G, int* __restrict__ bnd)
{
  const int blk = blockIdx.x, t = threadIdx.x;
  if (blk >= 163){
    int g = (blk - 163) * 256 + t;
    if (g > G) return;
    if (g == G){ bnd[G] = N; return; }
    int lo = 0, hi = N;
    while (lo < hi){ int mid = (lo + hi) >> 1; if (batch[mid] < g) lo = mid + 1; else hi = mid; }
    bnd[g] = lo;
    return;
  }
  const float *W, *as, *ad, *bl, *hlw, *hlb;
  float *cb;
  int FIN, b, layer;
  if (blk < 33){
    W = W1; as = a1s; ad = a1d; bl = b1; hlw = h1w; hlb = h1b;
    cb = cb1; FIN = 32; b = blk; layer = 1;
  } else if (blk < 98){
    W = W2; as = a2s; ad = a2d; bl = b2; hlw = h2w; hlb = h2b;
    cb = cb2; FIN = 64; b = blk - 33; layer = 2;
  } else {
    W = W3; as = a3s; ad = a3d; bl = b3; hlw = h3w; hlb = h3b;
    cb = cb3; FIN = 64; b = blk - 98; layer = 3;
  }
  if (b < FIN){
    const int c = t >> 2, h = t & 3;
    const float* wrow = W + b * GHC + h * 64;
    float acc = 0.f;
    #pragma unroll 8
    for (int j = 0; j < 64; j++)
      acc += wrow[j] * hlw[(h * 64 + j) * CH + c];
    const int k = h * FIN + b;
    if (layer == 3){
      Wcp3[k * CH + c] = acc;
    } else {
      int ks = k >> 5, nt = c >> 4;
      int lane = (((k & 31) >> 3) << 4) | (c & 15);
      int idx = ((ks * 4 + nt) * 64 + lane) * 8 + (k & 7);
      __half* Wpk = (layer == 1) ? Wpk1 : Wpk2;
      Wpk[idx] = __float2half(acc);
    }
    if (t < 8){
      const int hh = t & 3;
      const float* a = (t < 4) ? as : ad;
      const float* wr2 = W + b * GHC + hh * 64;
      float p = 0.f;
      #pragma unroll 8
      for (int j = 0; j < 64; j++) p += wr2[j] * a[hh * 64 + j];
      if (layer == 1){
        Psd1[b * 8 + t] = p;
      } else {
        int kk = b;
        int ks = kk >> 5;
        int lane = (((kk & 31) >> 3) << 4) | t;
        int idx = (ks * 64 + lane) * 8 + (kk & 7);
        __half* Ppk = (layer == 2) ? Ppk2 : Ppk3;
        Ppk[idx] = __float2half(p);
      }
    }
  } else if (t < CH){
    float acc = hlb[t];
    for (int j = 0; j < GHC; j++) acc += bl[j] * hlw[j * CH + t];
    cb[t] = acc;
  }
}

// ---------------- layer-1 logits from raw x + fp16 cast of x ----------------
__global__ __launch_bounds__(256)
void logits_from_x(const float* __restrict__ x, const float* __restrict__ Psd,
                   float* __restrict__ s_log, float* __restrict__ d_log,
                   __half* __restrict__ xh0, int N)
{
  int idx = blockIdx.x * 256 + threadIdx.x;
  int node = idx >> 3, q = idx & 7;
  if (node >= N) return;
  const float* xr = x + (size_t)node * 32;
  float v = 0.f;
  #pragma unroll 8
  for (int k = 0; k < 32; k++) v += xr[k] * Psd[k * 8 + q];
  if (q < 4){
    s_log[node * 4 + q] = v;
    __half2 h0 = __floats2half2_rn(xr[q*8+0], xr[q*8+1]);
    __half2 h1 = __floats2half2_rn(xr[q*8+2], xr[q*8+3]);
    __half2 h2 = __floats2half2_rn(xr[q*8+4], xr[q*8+5]);
    __half2 h3 = __floats2half2_rn(xr[q*8+6], xr[q*8+7]);
    uint4 u;
    u.x = *reinterpret_cast<const unsigned*>(&h0);
    u.y = *reinterpret_cast<const unsigned*>(&h1);
    u.z = *reinterpret_cast<const unsigned*>(&h2);
    u.w = *reinterpret_cast<const unsigned*>(&h3);
    *reinterpret_cast<uint4*>(xh0 + (size_t)node * 32 + q * 8) = u;
  } else {
    d_log[node * 4 + (q - 4)] = v;
  }
}

// ================= fused layer (degree-sorted): aggregate + MFMA transform =================
template<int F, int ZW>
__global__ __launch_bounds__(512)
void gat_layer_fused(const __half* __restrict__ xin, const float* __restrict__ s_in,
                     const float* __restrict__ d_in_, const int* __restrict__ off,
                     const unsigned short* __restrict__ csr, const int* __restrict__ perm,
                     const __half* __restrict__ Wpk, const float* __restrict__ cb,
                     const __half* __restrict__ Ppk,
                     __half* __restrict__ xo, float* __restrict__ s_out,
                     float* __restrict__ d_out_, int N)
{
  constexpr int ZP = ZW + 8;
  __shared__ float4 qa[8][2][32];
  __shared__ int    qs[8][2][32];
  __shared__ __half z_lds[16][ZP];
  __shared__ float  outs[16][68];
  __shared__ float  cbs[64];
  __shared__ int    pnode[16];
  const int tid  = threadIdx.x;
  const int wv   = tid >> 6;
  const int lane = tid & 63;
  const int half = lane >> 5;
  const int l32  = lane & 31;
  const int n0 = blockIdx.x * 16;
  if (tid < 64) cbs[tid] = cb[tid];
  if (tid < 16) pnode[tid] = (n0 + tid < N) ? perm[n0 + tid] : 0;
  __syncthreads();

  const int li = wv * 2 + half;           // local node index 0..15
  const bool valid = (n0 + li) < N;
  const int n = pnode[li];

  // ---------------- phase 1: aggregation into z_lds ----------------
  int beg = 0, deg = 0;
  if (valid){ beg = off[n]; deg = off[n + 1] - beg; }

  float d4[4] = {0.f, 0.f, 0.f, 0.f};
  if (valid){
    float4 d4v = reinterpret_cast<const float4*>(d_in_)[n];
    d4[0] = d4v.x; d4[1] = d4v.y; d4[2] = d4v.z; d4[3] = d4v.w;
  }

  float den[4], ex[4];
  int s = 0;
  {
    const bool act = valid && (l32 < deg);
    if (act){
      s = csr[beg + l32];
      float4 sl = reinterpret_cast<const float4*>(s_in)[s];
      float t[4] = {sl.x, sl.y, sl.z, sl.w};
      #pragma unroll
      for (int i = 0; i < 4; i++){
        float u = t[i] + d4[i]; u = (u >= 0.f) ? u : NEG * u;
        ex[i] = __expf(u);
      }
    } else {
      #pragma unroll
      for (int i = 0; i < 4; i++) ex[i] = 0.f;
    }
    #pragma unroll
    for (int i = 0; i < 4; i++) den[i] = wsum32(ex[i]);
  }
  for (int base = 32; base < deg; base += 32){
    const int k = base + l32;
    float e2[4] = {0.f, 0.f, 0.f, 0.f};
    if (k < deg){
      int s2 = csr[beg + k];
      float4 sl = reinterpret_cast<const float4*>(s_in)[s2];
      float t[4] = {sl.x, sl.y, sl.z, sl.w};
      #pragma unroll
      for (int i = 0; i < 4; i++){
        float u = t[i] + d4[i]; u = (u >= 0.f) ? u : NEG * u;
        e2[i] = __expf(u);
      }
    }
    #pragma unroll
    for (int i = 0; i < 4; i++) den[i] += wsum32(e2[i]);
  }

  float dninv[4];
  #pragma unroll
  for (int i = 0; i < 4; i++) dninv[i] = 1.f / fmaxf(den[i], 1e-16f);

  float a0[4] = {0.f,0.f,0.f,0.f};
  float a1[4] = {0.f,0.f,0.f,0.f};
  const float4* qap = qa[wv][half];
  const int*    qsp = qs[wv][half];

  auto accum = [&](int cnt){
    int cntR = (cnt + 3) & ~3;
    if (F == 64){
      const __half* xb = xin + 2 * l32;
      for (int e0 = 0; e0 < cntR; e0 += 4){
        float4 al[4]; int sv[4]; unsigned uv[4];
        #pragma unroll
        for (int j = 0; j < 4; j++){ al[j] = qap[e0 + j]; sv[j] = qsp[e0 + j]; }
        #pragma unroll
        for (int j = 0; j < 4; j++)
          uv[j] = *reinterpret_cast<const unsigned*>(xb + sv[j] * 64);
        #pragma unroll
        for (int j = 0; j < 4; j++){
          float2 f = __half22float2(*reinterpret_cast<const __half2*>(&uv[j]));
          a0[0] += al[j].x * f.x; a1[0] += al[j].x * f.y;
          a0[1] += al[j].y * f.x; a1[1] += al[j].y * f.y;
          a0[2] += al[j].z * f.x; a1[2] += al[j].z * f.y;
          a0[3] += al[j].w * f.x; a1[3] += al[j].w * f.y;
        }
      }
    } else {
      const __half* xb = xin + l32;
      for (int e0 = 0; e0 < cntR; e0 += 4){
        float4 al[4]; int sv[4]; __half hv[4];
        #pragma unroll
        for (int j = 0; j < 4; j++){ al[j] = qap[e0 + j]; sv[j] = qsp[e0 + j]; }
        #pragma unroll
        for (int j = 0; j < 4; j++)
          hv[j] = xb[sv[j] * 32];
        #pragma unroll
        for (int j = 0; j < 4; j++){
          float xv = __half2float(hv[j]);
          a0[0] += al[j].x * xv;
          a0[1] += al[j].y * xv;
          a0[2] += al[j].z * xv;
          a0[3] += al[j].w * xv;
        }
      }
    }
  };

  if (deg <= 32){
    qa[wv][half][l32] = make_float4(ex[0] * dninv[0], ex[1] * dninv[1],
                                    ex[2] * dninv[2], ex[3] * dninv[3]);
    qs[wv][half][l32] = s;
    WAVE_SYNC();
    accum(deg);
  } else {
    for (int base = 0; base < deg; base += 32){
      const int k = base + l32;
      int s2 = 0; float al[4] = {0.f, 0.f, 0.f, 0.f};
      if (k < deg){
        s2 = csr[beg + k];
        float4 sl = reinterpret_cast<const float4*>(s_in)[s2];
        float t[4] = {sl.x, sl.y, sl.z, sl.w};
        #pragma unroll
        for (int i = 0; i < 4; i++){
          float u = t[i] + d4[i]; u = (u >= 0.f) ? u : NEG * u;
          al[i] = __expf(u) * dninv[i];
        }
      }
      qa[wv][half][l32] = make_float4(al[0], al[1], al[2], al[3]);
      qs[wv][half][l32] = s2;
      WAVE_SYNC();
      accum(min(32, deg - base));
      WAVE_SYNC();
    }
  }

  {
    const int r = li;
    if (F == 64){
      #pragma unroll
      for (int h = 0; h < 4; h++){
        __half2 hv = __floats2half2_rn(a0[h], a1[h]);
        *reinterpret_cast<unsigned*>(&z_lds[r][h * 64 + 2 * l32]) =
            *reinterpret_cast<const unsigned*>(&hv);
      }
    } else {
      #pragma unroll
      for (int h = 0; h < 4; h++)
        z_lds[r][h * 32 + l32] = __float2half(a0[h]);
    }
  }
  __syncthreads();

  // ---------------- phase 2: MFMA transform (waves 0-3) ----------------
  const int row = lane & 15, kg = lane >> 4;
  if (wv < 4){
    const int nt = wv;
    f32x4 acc = {0.f,0.f,0.f,0.f};
    const f16x8* wp = reinterpret_cast<const f16x8*>(Wpk) + lane;
    #pragma unroll
    for (int ks = 0; ks < ZW / 32; ks++){
      f16x8 af = *reinterpret_cast<const f16x8*>(&z_lds[row][kg * 8 + ks * 32]);
      acc = __builtin_amdgcn_mfma_f32_16x16x32_f16(af, wp[(ks*4+nt)*64], acc, 0,0,0);
    }
    #pragma unroll
    for (int r = 0; r < 4; r++){
      int rr = kg * 4 + r;
      outs[rr][nt * 16 + row] = fmaxf(acc[r] + cbs[nt * 16 + row], 0.f);
    }
  }
  __syncthreads();

  if (tid < 256){
    int nn = tid >> 4, part = tid & 15;
    if (n0 + nn < N){
      int node = pnode[nn];
      const float* o = &outs[nn][part * 4];
      __half2 h0 = __floats2half2_rn(o[0], o[1]);
      __half2 h1 = __floats2half2_rn(o[2], o[3]);
      uint2 u;
      u.x = *reinterpret_cast<const unsigned*>(&h0);
      u.y = *reinterpret_cast<const unsigned*>(&h1);
      *reinterpret_cast<uint2*>(xo + (size_t)node * 64 + part * 4) = u;
    }
  }

  if (wv == 4){
    f32x4 lacc = {0.f,0.f,0.f,0.f};
    const f16x8* pp = reinterpret_cast<const f16x8*>(Ppk) + lane;
    #pragma unroll
    for (int ks = 0; ks < 2; ks++){
      f16x8 af;
      #pragma unroll
      for (int j = 0; j < 8; j++) af[j] = (_Float16)outs[row][ks * 32 + kg * 8 + j];
      lacc = __builtin_amdgcn_mfma_f32_16x16x32_f16(af, pp[ks * 64], lacc, 0,0,0);
    }
    if (row < 8){
      float* dst = (row < 4) ? s_out : d_out_;
      int q = row & 3;
      #pragma unroll
      for (int r = 0; r < 4; r++){
        if (n0 + kg * 4 + r < N){
          int node = pnode[kg * 4 + r];
          dst[node * 4 + q] = lacc[r];
        }
      }
    }
  }
}

// ---------------- layer-3 aggregation (degree-sorted, z to global) ----------------
__global__ __launch_bounds__(256)
void gat_aggregate_z3(const __half* __restrict__ xin, const float* __restrict__ s_log,
                      const float* __restrict__ d_log, const int* __restrict__ off,
                      const unsigned short* __restrict__ csr, const int* __restrict__ perm,
                      __half* __restrict__ z, int N)
{
  __shared__ float4 qa[4][2][32];
  __shared__ int    qs[4][2][32];
  const int wv   = threadIdx.x >> 6;
  const int lane = threadIdx.x & 63;
  const int half = lane >> 5;
  const int l32  = lane & 31;
  const int idx = blockIdx.x * 8 + wv * 2 + half;
  const bool valid = idx < N;
  const int n = valid ? perm[idx] : 0;

  int beg = 0, deg = 0;
  if (valid){ beg = off[n]; deg = off[n + 1] - beg; }

  float d4[4] = {0.f, 0.f, 0.f, 0.f};
  if (valid){
    float4 d4v = reinterpret_cast<const float4*>(d_log)[n];
    d4[0] = d4v.x; d4[1] = d4v.y; d4[2] = d4v.z; d4[3] = d4v.w;
  }

  float den[4], ex[4];
  int s = 0;
  {
    const bool act = valid && (l32 < deg);
    if (act){
      s = csr[beg + l32];
      float4 sl = reinterpret_cast<const float4*>(s_log)[s];
      float t[4] = {sl.x, sl.y, sl.z, sl.w};
      #pragma unroll
      for (int i = 0; i < 4; i++){
        float u = t[i] + d4[i]; u = (u >= 0.f) ? u : NEG * u;
        ex[i] = __expf(u);
      }
    } else {
      #pragma unroll
      for (int i = 0; i < 4; i++) ex[i] = 0.f;
    }
    #pragma unroll
    for (int i = 0; i < 4; i++) den[i] = wsum32(ex[i]);
  }
  for (int base = 32; base < deg; base += 32){
    const int k = base + l32;
    float e2[4] = {0.f, 0.f, 0.f, 0.f};
    if (k < deg){
      int s2 = csr[beg + k];
      float4 sl = reinterpret_cast<const float4*>(s_log)[s2];
      float t[4] = {sl.x, sl.y, sl.z, sl.w};
      #pragma unroll
      for (int i = 0; i < 4; i++){
        float u = t[i] + d4[i]; u = (u >= 0.f) ? u : NEG * u;
        e2[i] = __expf(u);
      }
    }
    #pragma unroll
    for (int i = 0; i < 4; i++) den[i] += wsum32(e2[i]);
  }

  float dninv[4];
  #pragma unroll
  for (int i = 0; i < 4; i++) dninv[i] = 1.f / fmaxf(den[i], 1e-16f);

  float a0[4] = {0.f,0.f,0.f,0.f};
  float a1[4] = {0.f,0.f,0.f,0.f};
  const float4* qap = qa[wv][half];
  const int*    qsp = qs[wv][half];

  auto accum = [&](int cnt){
    int cntR = (cnt + 3) & ~3;
    const __half* xb = xin + 2 * l32;
    for (int e0 = 0; e0 < cntR; e0 += 4){
      float4 al[4]; int sv[4]; unsigned uv[4];
      #pragma unroll
      for (int j = 0; j < 4; j++){ al[j] = qap[e0 + j]; sv[j] = qsp[e0 + j]; }
      #pragma unroll
      for (int j = 0; j < 4; j++)
        uv[j] = *reinterpret_cast<const unsigned*>(xb + sv[j] * 64);
      #pragma unroll
      for (int j = 0; j < 4; j++){
        float2 f = __half22float2(*reinterpret_cast<const __half2*>(&uv[j]));
        a0[0] += al[j].x * f.x; a1[0] += al[j].x * f.y;
        a0[1] += al[j].y * f.x; a1[1] += al[j].y * f.y;
        a0[2] += al[j].z * f.x; a1[2] += al[j].z * f.y;
        a0[3] += al[j].w * f.x; a1[3] += al[j].w * f.y;
      }
    }
  };

  if (deg <= 32){
    qa[wv][half][l32] = make_float4(ex[0] * dninv[0], ex[1] * dninv[1],
                                    ex[2] * dninv[2], ex[3] * dninv[3]);
    qs[wv][half][l32] = s;
    WAVE_SYNC();
    accum(deg);
  } else {
    for (int base = 0; base < deg; base += 32){
      const int k = base + l32;
      int s2 = 0; float al[4] = {0.f, 0.f, 0.f, 0.f};
      if (k < deg){
        s2 = csr[beg + k];
        float4 sl = reinterpret_cast<const float4*>(s_log)[s2];
        float t[4] = {sl.x, sl.y, sl.z, sl.w};
        #pragma unroll
        for (int i = 0; i < 4; i++){
          float u = t[i] + d4[i]; u = (u >= 0.f) ? u : NEG * u;
          al[i] = __expf(u) * dninv[i];
        }
      }
      qa[wv][half][l32] = make_float4(al[0], al[1], al[2], al[3]);
      qs[wv][half][l32] = s2;
      WAVE_SYNC();
      accum(min(32, deg - base));
      WAVE_SYNC();
    }
  }

  if (valid){
    const size_t zb = (size_t)n * 256 + 2 * l32;
    #pragma unroll
    for (int h = 0; h < 4; h++){
      __half2 hv = __floats2half2_rn(a0[h], a1[h]);
      *reinterpret_cast<unsigned*>(z + zb + h * 64) =
          *reinterpret_cast<const unsigned*>(&hv);
    }
  }
}

// ---------------- pooling (4-way split) + MLP head ----------------
__global__ __launch_bounds__(256)
void pool_partial(const __half* __restrict__ z3, const int* __restrict__ bnd,
                  float* __restrict__ psum)
{
  const int blk = blockIdx.x, tid = threadIdx.x;
  const int g = blk >> 2, part = blk & 3;
  const int s = bnd[g], e = bnd[g + 1];
  const int cp = tid & 127, rp = tid >> 7;
  float ax = 0.f, ay = 0.f;
  for (int n = s + part + 4 * rp; n < e; n += 8){
    __half2 hv = *reinterpret_cast<const __half2*>(z3 + (size_t)n * 256 + 2 * cp);
    float2 f = __half22float2(hv);
    ax += f.x; ay += f.y;
  }
  __shared__ float shx[2][128], shy[2][128];
  shx[rp][cp] = ax; shy[rp][cp] = ay;
  __syncthreads();
  if (tid < 128){
    psum[(size_t)blk * 256 + 2 * tid]     = shx[0][tid] + shx[1][tid];
    psum[(size_t)blk * 256 + 2 * tid + 1] = shy[0][tid] + shy[1][tid];
  }
}

__global__ __launch_bounds__(256)
void head_mlp(const float* __restrict__ psum, const int* __restrict__ bnd,
              const float* __restrict__ Wcp3, const float* __restrict__ cb3,
              const float* __restrict__ m1w, const float* __restrict__ m1b,
              const float* __restrict__ m2w, const float* __restrict__ m2b,
              float* __restrict__ out)
{
  const int g = blockIdx.x, tid = threadIdx.x;
  const float cnt = (float)max(bnd[g + 1] - bnd[g], 1);
  __shared__ float zbar[256];
  const float* pb = psum + (size_t)g * 1024;
  zbar[tid] = (pb[tid] + pb[256 + tid] + pb[512 + tid] + pb[768 + tid]) / cnt;
  __syncthreads();
  const int c = tid & 63, part = tid >> 6;
  float tp = 0.f;
  #pragma unroll 8
  for (int k = part * 64; k < part * 64 + 64; k++) tp += zbar[k] * Wcp3[k * 64 + c];
  __shared__ float tsh[4][64];
  tsh[part][c] = tp;
  __syncthreads();
  __shared__ float tvec[64];
  if (tid < 64)
    tvec[tid] = tsh[0][tid] + tsh[1][tid] + tsh[2][tid] + tsh[3][tid] + cb3[tid];
  __syncthreads();
  float a = m1b[tid];
  #pragma unroll 8
  for (int cc = 0; cc < 64; cc++) a += tvec[cc] * m1w[cc * 256 + tid];
  __shared__ float g1row[256];
  g1row[tid] = fmaxf(a, 0.f);
  __syncthreads();
  float o = m2b[tid];
  #pragma unroll 8
  for (int k = 0; k < 256; k++) o += g1row[k] * m2w[k * 256 + tid];
  out[g * 256 + tid] = o;
}

// ---------------- launcher ----------------
extern "C" void kernel_launch(void* const* d_in, const int* in_sizes, int n_in,
                              void* d_out, int out_size, void* d_ws, size_t ws_size,
                              hipStream_t stream)
{
  const float* x     = (const float*)d_in[0];
  const int*   ei    = (const int*)d_in[1];
  const int*   batch = (const int*)d_in[2];
  const float* W1  = (const float*)d_in[4];
  const float* a1s = (const float*)d_in[5];
  const float* a1d = (const float*)d_in[6];
  const float* b1  = (const float*)d_in[7];
  const float* h1w = (const float*)d_in[8];
  const float* h1b = (const float*)d_in[9];
  const float* W2  = (const float*)d_in[10];
  const float* a2s = (const float*)d_in[11];
  const float* a2d = (const float*)d_in[12];
  const float* b2  = (const float*)d_in[13];
  const float* h2w = (const float*)d_in[14];
  const float* h2b = (const float*)d_in[15];
  const float* W3  = (const float*)d_in[16];
  const float* a3s = (const float*)d_in[17];
  const float* a3d = (const float*)d_in[18];
  const float* b3  = (const float*)d_in[19];
  const float* h3w = (const float*)d_in[20];
  const float* h3b = (const float*)d_in[21];
  const float* m1w = (const float*)d_in[22];
  const float* m1b = (const float*)d_in[23];
  const float* m2w = (const float*)d_in[24];
  const float* m2b = (const float*)d_in[25];

  const int N = in_sizes[0] / 32;
  const int E = in_sizes[1] / 2;
  const int G = out_size / 256;
  const int Etot = E + N;
  const int nbuck = (N + 255) >> 8;

  char* p = (char*)d_ws;
  auto alloc = [&](size_t bytes) -> void* {
    void* r = (void*)p;
    p += ((bytes + 255) / 256) * 256;
    return r;
  };
  __half* zbuf   = (__half*)alloc((size_t)N * GHC * 2);
  __half* xh0    = (__half*)alloc((size_t)N * 32 * 2);
  __half* xh1    = (__half*)alloc((size_t)N * CH * 2);
  __half* xh2    = (__half*)alloc((size_t)N * CH * 2);
  float* s_logA  = (float*)alloc((size_t)N * HD * 4);
  float* d_logA  = (float*)alloc((size_t)N * HD * 4);
  float* s_logB  = (float*)alloc((size_t)N * HD * 4);
  float* d_logB  = (float*)alloc((size_t)N * HD * 4);
  int*   offs    = (int*)alloc((size_t)(N + 1) * 4);
  int*   perm    = (int*)alloc((size_t)N * 4);
  unsigned short* csr = (unsigned short*)alloc((size_t)Etot * 2);
  unsigned* pairs = (unsigned*)alloc((size_t)nbuck * BCAP * 4);
  // contiguous zero-init: bres(1K) Ppk2(2K) Ppk3(2K) ghist(1K) gbincnt(1K)
  int*    bres   = (int*)alloc(256 * 4);
  __half* Ppk2   = (__half*)alloc(1024 * 2);
  __half* Ppk3   = (__half*)alloc(1024 * 2);
  int*    ghist  = (int*)alloc(256 * 4);
  int*    gbincnt= (int*)alloc(256 * 4);
  int*   bnd     = (int*)alloc((size_t)(G + 1) * 4);
  float* psum    = (float*)alloc((size_t)G * 4 * 256 * 4);
  float* Wcp3    = (float*)alloc(256 * 64 * 4);
  float* Psd1    = (float*)alloc(32 * 8 * 4);
  float* cb1     = (float*)alloc(64 * 4);
  float* cb2     = (float*)alloc(64 * 4);
  float* cb3     = (float*)alloc(64 * 4);
  __half* Wpk1   = (__half*)alloc(128 * 64 * 2);
  __half* Wpk2   = (__half*)alloc(256 * 64 * 2);

  hipMemsetAsync(bres, 0, 7168, stream);   // bres + Ppk2 + Ppk3 + ghist + gbincnt

  const int cb_blocks = (Etot + CHUNK - 1) / CHUNK;
  bin_stage<<<cb_blocks, 256, 0, stream>>>(ei, E, N, bres, pairs);
  build_csr<<<nbuck, 256, 0, stream>>>(pairs, bres, N, Etot, offs, csr, ghist);
  perm_scatter<<<nbuck, 256, 0, stream>>>(offs, ghist, gbincnt, perm, N);

  const int fb = 163 + (G + 256) / 256;
  fuse_all<<<fb, 256, 0, stream>>>(W1, a1s, a1d, b1, h1w, h1b,
                                   W2, a2s, a2d, b2, h2w, h2b,
                                   W3, a3s, a3d, b3, h3w, h3b,
                                   Wpk1, Psd1, cb1, Wpk2, Ppk2, cb2, Wcp3, Ppk3, cb3,
                                   batch, N, G, bnd);

  logits_from_x<<<((size_t)N * 8 + 255) / 256, 256, 0, stream>>>(x, Psd1, s_logA, d_logA, xh0, N);

  const int fgrid = (N + 15) / 16;
  gat_layer_fused<32, 128><<<fgrid, 512, 0, stream>>>(xh0, s_logA, d_logA, offs, csr, perm,
                                                      Wpk1, cb1, Ppk2, xh1, s_logB, d_logB, N);
  gat_layer_fused<64, 256><<<fgrid, 512, 0, stream>>>(xh1, s_logB, d_logB, offs, csr, perm,
                                                      Wpk2, cb2, Ppk3, xh2, s_logA, d_logA, N);

  const int ab = (N + 7) / 8;
  gat_aggregate_z3<<<ab, 256, 0, stream>>>(xh2, s_logA, d_logA, offs, csr, perm, zbuf, N);

  pool_partial<<<G * 4, 256, 0, stream>>>(zbuf, bnd, psum);
  head_mlp<<<G, 256, 0, stream>>>(psum, bnd, Wcp3, cb3, m1w, m1b, m2w, m2b, (float*)d_out);
}

// Round 21
// 175.011 us; speedup vs baseline: 2.5559x; 2.5559x over previous
//
#include <hip/hip_runtime.h>
#include <hip/hip_bf16.h>
#include <hip/hip_fp16.h>
#include <math.h>

#define HD 4
#define CH 64
#define GHC 256
#define NEG 0.2f
#define CHUNK 4096
#define BCAP 16384

#define WAVE_SYNC() do { __builtin_amdgcn_wave_barrier(); \
                         asm volatile("s_waitcnt lgkmcnt(0)" ::: "memory"); } while (0)

typedef _Float16 f16x8 __attribute__((ext_vector_type(8)));
typedef float f32x4 __attribute__((ext_vector_type(4)));

__device__ __forceinline__ float wsum32(float v){
  #pragma unroll
  for (int o = 16; o > 0; o >>= 1) v += __shfl_xor(v, o);
  return v;
}

// ---------------- CSR build (bucket-based) ----------------
__global__ __launch_bounds__(256)
void bin_stage(const int* __restrict__ ei, int E, int N,
               int* __restrict__ bres, unsigned* __restrict__ pairs)
{
  __shared__ unsigned staged[CHUNK];
  __shared__ unsigned short bkt[CHUNK];
  __shared__ int cnts[256], loff[256], gpos[256];
  const int t = threadIdx.x;
  const int tot = E + N;
  const int cbase = blockIdx.x * CHUNK;
  if (cbase >= tot) return;

  cnts[t] = 0;
  __syncthreads();

  unsigned myp[CHUNK / 256];
  int myb[CHUNK / 256], myr[CHUNK / 256];
  #pragma unroll
  for (int j = 0; j < CHUNK / 256; j++){
    int i = cbase + t + j * 256;
    myb[j] = -1;
    if (i < tot){
      int src, dst;
      if (i < E){ src = ei[i]; dst = ei[E + i]; }
      else { src = dst = i - E; }
      myb[j] = dst >> 8;
      myp[j] = (unsigned)src | ((unsigned)dst << 16);
      myr[j] = atomicAdd(&cnts[myb[j]], 1);
    }
  }
  __syncthreads();

  int v = cnts[t];
  loff[t] = v;
  __syncthreads();
  for (int o = 1; o < 256; o <<= 1){
    int tv = (t >= o) ? loff[t - o] : 0;
    __syncthreads();
    loff[t] += tv;
    __syncthreads();
  }
  int excl = loff[t] - v;
  __syncthreads();
  loff[t] = excl;
  __syncthreads();

  #pragma unroll
  for (int j = 0; j < CHUNK / 256; j++){
    if (myb[j] >= 0){
      int slot = loff[myb[j]] + myr[j];
      staged[slot] = myp[j];
      bkt[slot] = (unsigned short)myb[j];
    }
  }
  if (v > 0) gpos[t] = atomicAdd(&bres[t], v);
  __syncthreads();

  int total = min(CHUNK, tot - cbase);
  for (int i = t; i < total; i += 256){
    int b = bkt[i];
    int addr = b * BCAP + gpos[b] + (i - loff[b]);
    pairs[addr] = staged[i];
  }
}

__global__ __launch_bounds__(256)
void build_csr(const unsigned* __restrict__ pairs, const int* __restrict__ bres,
               int N, int Etot, int* __restrict__ offs, unsigned short* __restrict__ csr,
               int* __restrict__ ghist)
{
  __shared__ int dcnt[256], doff[256], bscan[256], hcnt[256];
  const int b = blockIdx.x, t = threadIdx.x;
  int bv = bres[t];
  bscan[t] = bv;
  hcnt[t] = 0;
  __syncthreads();
  for (int o = 1; o < 256; o <<= 1){
    int tv = (t >= o) ? bscan[t - o] : 0;
    __syncthreads();
    bscan[t] += tv;
    __syncthreads();
  }
  const int beg = bscan[b] - bres[b];
  const int cnt = bres[b];
  const unsigned* pb = pairs + (size_t)b * BCAP;
  dcnt[t] = 0;
  __syncthreads();
  for (int i = t; i < cnt; i += 256)
    atomicAdd(&dcnt[(pb[i] >> 16) & 255], 1);
  __syncthreads();
  int v = dcnt[t];
  doff[t] = v;
  __syncthreads();
  for (int o = 1; o < 256; o <<= 1){
    int tv = (t >= o) ? doff[t - o] : 0;
    __syncthreads();
    doff[t] += tv;
    __syncthreads();
  }
  int excl = doff[t] - v;
  __syncthreads();
  doff[t] = excl;
  __syncthreads();
  int node = (b << 8) + t;
  if (node < N){
    offs[node] = beg + doff[t];
    atomicAdd(&hcnt[min(v, 255)], 1);   // LDS-aggregated degree histogram
  }
  if (b == 0 && t == 0) offs[N] = Etot;
  dcnt[t] = 0;
  __syncthreads();
  if (hcnt[t] > 0) atomicAdd(&ghist[t], hcnt[t]);   // <=256 adds/block, spread
  for (int i = t; i < cnt; i += 256){
    unsigned pr = pb[i];
    int l = (pr >> 16) & 255;
    int pos = beg + doff[l] + atomicAdd(&dcnt[l], 1);
    csr[pos] = (unsigned short)(pr & 0xFFFF);
  }
}

// counting-sort scatter with BLOCK-AGGREGATED span reservation:
// LDS hist of this block's bins -> one global atomic per bin per block.
// Within-bin order is arbitrary (per-node outputs are order-invariant).
__global__ __launch_bounds__(256)
void perm_scatter(const int* __restrict__ offs, const int* __restrict__ ghist,
                  int* __restrict__ gbincnt, int* __restrict__ perm, int N)
{
  __shared__ int sc[256], gbase[256], lh[256], lbase[256];
  const int t = threadIdx.x;
  int v = ghist[t];
  sc[t] = v;
  lh[t] = 0;
  __syncthreads();
  for (int o = 1; o < 256; o <<= 1){
    int tv = (t >= o) ? sc[t - o] : 0;
    __syncthreads();
    sc[t] += tv;
    __syncthreads();
  }
  gbase[t] = sc[t] - v;
  __syncthreads();
  int node = blockIdx.x * 256 + t;
  int bin = -1, r = 0;
  if (node < N){
    int deg = offs[node + 1] - offs[node];
    bin = min(deg, 255);
    r = atomicAdd(&lh[bin], 1);
  }
  __syncthreads();
  if (lh[t] > 0) lbase[t] = atomicAdd(&gbincnt[t], lh[t]);
  __syncthreads();
  if (node < N)
    perm[gbase[bin] + lbase[bin] + r] = node;
}

// ---------------- fused-weight precompute + MFMA packing + graph bounds ----------------
__global__ __launch_bounds__(256)
void fuse_all(const float* __restrict__ W1, const float* __restrict__ a1s,
              const float* __restrict__ a1d, const float* __restrict__ b1,
              const float* __restrict__ h1w, const float* __restrict__ h1b,
              const float* __restrict__ W2, const float* __restrict__ a2s,
              const float* __restrict__ a2d, const float* __restrict__ b2,
              const float* __restrict__ h2w, const float* __restrict__ h2b,
              const float* __restrict__ W3, const float* __restrict__ a3s,
              const float* __restrict__ a3d, const float* __restrict__ b3,
              const float* __restrict__ h3w, const float* __restrict__ h3b,
              __half* __restrict__ Wpk1, float* __restrict__ Psd1, float* __restrict__ cb1,
              __half* __restrict__ Wpk2, __half* __restrict__ Ppk2, float* __restrict__ cb2,
              float* __restrict__ Wcp3, __half* __restrict__ Ppk3, float* __restrict__ cb3,
              const int* __restrict__ batch, int N, int G, int* __restrict__ bnd)
{
  const int blk = blockIdx.x, t = threadIdx.x;
  if (blk >= 163){
    int g = (blk - 163) * 256 + t;
    if (g > G) return;
    if (g == G){ bnd[G] = N; return; }
    int lo = 0, hi = N;
    while (lo < hi){ int mid = (lo + hi) >> 1; if (batch[mid] < g) lo = mid + 1; else hi = mid; }
    bnd[g] = lo;
    return;
  }
  const float *W, *as, *ad, *bl, *hlw, *hlb;
  float *cb;
  int FIN, b, layer;
  if (blk < 33){
    W = W1; as = a1s; ad = a1d; bl = b1; hlw = h1w; hlb = h1b;
    cb = cb1; FIN = 32; b = blk; layer = 1;
  } else if (blk < 98){
    W = W2; as = a2s; ad = a2d; bl = b2; hlw = h2w; hlb = h2b;
    cb = cb2; FIN = 64; b = blk - 33; layer = 2;
  } else {
    W = W3; as = a3s; ad = a3d; bl = b3; hlw = h3w; hlb = h3b;
    cb = cb3; FIN = 64; b = blk - 98; layer = 3;
  }
  if (b < FIN){
    const int c = t >> 2, h = t & 3;
    const float* wrow = W + b * GHC + h * 64;
    float acc = 0.f;
    #pragma unroll 8
    for (int j = 0; j < 64; j++)
      acc += wrow[j] * hlw[(h * 64 + j) * CH + c];
    const int k = h * FIN + b;
    if (layer == 3){
      Wcp3[k * CH + c] = acc;
    } else {
      int ks = k >> 5, nt = c >> 4;
      int lane = (((k & 31) >> 3) << 4) | (c & 15);
      int idx = ((ks * 4 + nt) * 64 + lane) * 8 + (k & 7);
      __half* Wpk = (layer == 1) ? Wpk1 : Wpk2;
      Wpk[idx] = __float2half(acc);
    }
    if (t < 8){
      const int hh = t & 3;
      const float* a = (t < 4) ? as : ad;
      const float* wr2 = W + b * GHC + hh * 64;
      float p = 0.f;
      #pragma unroll 8
      for (int j = 0; j < 64; j++) p += wr2[j] * a[hh * 64 + j];
      if (layer == 1){
        Psd1[b * 8 + t] = p;
      } else {
        int kk = b;
        int ks = kk >> 5;
        int lane = (((kk & 31) >> 3) << 4) | t;
        int idx = (ks * 64 + lane) * 8 + (kk & 7);
        __half* Ppk = (layer == 2) ? Ppk2 : Ppk3;
        Ppk[idx] = __float2half(p);
      }
    }
  } else if (t < CH){
    float acc = hlb[t];
    for (int j = 0; j < GHC; j++) acc += bl[j] * hlw[j * CH + t];
    cb[t] = acc;
  }
}

// ---------------- layer-1 logits from raw x + fp16 cast of x ----------------
__global__ __launch_bounds__(256)
void logits_from_x(const float* __restrict__ x, const float* __restrict__ Psd,
                   float* __restrict__ s_log, float* __restrict__ d_log,
                   __half* __restrict__ xh0, int N)
{
  int idx = blockIdx.x * 256 + threadIdx.x;
  int node = idx >> 3, q = idx & 7;
  if (node >= N) return;
  const float* xr = x + (size_t)node * 32;
  float v = 0.f;
  #pragma unroll 8
  for (int k = 0; k < 32; k++) v += xr[k] * Psd[k * 8 + q];
  if (q < 4){
    s_log[node * 4 + q] = v;
    __half2 h0 = __floats2half2_rn(xr[q*8+0], xr[q*8+1]);
    __half2 h1 = __floats2half2_rn(xr[q*8+2], xr[q*8+3]);
    __half2 h2 = __floats2half2_rn(xr[q*8+4], xr[q*8+5]);
    __half2 h3 = __floats2half2_rn(xr[q*8+6], xr[q*8+7]);
    uint4 u;
    u.x = *reinterpret_cast<const unsigned*>(&h0);
    u.y = *reinterpret_cast<const unsigned*>(&h1);
    u.z = *reinterpret_cast<const unsigned*>(&h2);
    u.w = *reinterpret_cast<const unsigned*>(&h3);
    *reinterpret_cast<uint4*>(xh0 + (size_t)node * 32 + q * 8) = u;
  } else {
    d_log[node * 4 + (q - 4)] = v;
  }
}

// ================= fused layer (degree-sorted): aggregate + MFMA transform =================
template<int F, int ZW>
__global__ __launch_bounds__(512)
void gat_layer_fused(const __half* __restrict__ xin, const float* __restrict__ s_in,
                     const float* __restrict__ d_in_, const int* __restrict__ off,
                     const unsigned short* __restrict__ csr, const int* __restrict__ perm,
                     const __half* __restrict__ Wpk, const float* __restrict__ cb,
                     const __half* __restrict__ Ppk,
                     __half* __restrict__ xo, float* __restrict__ s_out,
                     float* __restrict__ d_out_, int N)
{
  constexpr int ZP = ZW + 8;
  __shared__ float4 qa[8][2][32];
  __shared__ int    qs[8][2][32];
  __shared__ __half z_lds[16][ZP];
  __shared__ float  outs[16][68];
  __shared__ float  cbs[64];
  __shared__ int    pnode[16];
  const int tid  = threadIdx.x;
  const int wv   = tid >> 6;
  const int lane = tid & 63;
  const int half = lane >> 5;
  const int l32  = lane & 31;
  const int n0 = blockIdx.x * 16;
  if (tid < 64) cbs[tid] = cb[tid];
  if (tid < 16) pnode[tid] = (n0 + tid < N) ? perm[n0 + tid] : 0;
  __syncthreads();

  const int li = wv * 2 + half;
  const bool valid = (n0 + li) < N;
  const int n = pnode[li];

  int beg = 0, deg = 0;
  if (valid){ beg = off[n]; deg = off[n + 1] - beg; }

  float d4[4] = {0.f, 0.f, 0.f, 0.f};
  if (valid){
    float4 d4v = reinterpret_cast<const float4*>(d_in_)[n];
    d4[0] = d4v.x; d4[1] = d4v.y; d4[2] = d4v.z; d4[3] = d4v.w;
  }

  float den[4], ex[4];
  int s = 0;
  {
    const bool act = valid && (l32 < deg);
    if (act){
      s = csr[beg + l32];
      float4 sl = reinterpret_cast<const float4*>(s_in)[s];
      float t[4] = {sl.x, sl.y, sl.z, sl.w};
      #pragma unroll
      for (int i = 0; i < 4; i++){
        float u = t[i] + d4[i]; u = (u >= 0.f) ? u : NEG * u;
        ex[i] = __expf(u);
      }
    } else {
      #pragma unroll
      for (int i = 0; i < 4; i++) ex[i] = 0.f;
    }
    #pragma unroll
    for (int i = 0; i < 4; i++) den[i] = wsum32(ex[i]);
  }
  for (int base = 32; base < deg; base += 32){
    const int k = base + l32;
    float e2[4] = {0.f, 0.f, 0.f, 0.f};
    if (k < deg){
      int s2 = csr[beg + k];
      float4 sl = reinterpret_cast<const float4*>(s_in)[s2];
      float t[4] = {sl.x, sl.y, sl.z, sl.w};
      #pragma unroll
      for (int i = 0; i < 4; i++){
        float u = t[i] + d4[i]; u = (u >= 0.f) ? u : NEG * u;
        e2[i] = __expf(u);
      }
    }
    #pragma unroll
    for (int i = 0; i < 4; i++) den[i] += wsum32(e2[i]);
  }

  float dninv[4];
  #pragma unroll
  for (int i = 0; i < 4; i++) dninv[i] = 1.f / fmaxf(den[i], 1e-16f);

  float a0[4] = {0.f,0.f,0.f,0.f};
  float a1[4] = {0.f,0.f,0.f,0.f};
  const float4* qap = qa[wv][half];
  const int*    qsp = qs[wv][half];

  auto accum = [&](int cnt){
    int cntR = (cnt + 3) & ~3;
    if (F == 64){
      const __half* xb = xin + 2 * l32;
      for (int e0 = 0; e0 < cntR; e0 += 4){
        float4 al[4]; int sv[4]; unsigned uv[4];
        #pragma unroll
        for (int j = 0; j < 4; j++){ al[j] = qap[e0 + j]; sv[j] = qsp[e0 + j]; }
        #pragma unroll
        for (int j = 0; j < 4; j++)
          uv[j] = *reinterpret_cast<const unsigned*>(xb + sv[j] * 64);
        #pragma unroll
        for (int j = 0; j < 4; j++){
          float2 f = __half22float2(*reinterpret_cast<const __half2*>(&uv[j]));
          a0[0] += al[j].x * f.x; a1[0] += al[j].x * f.y;
          a0[1] += al[j].y * f.x; a1[1] += al[j].y * f.y;
          a0[2] += al[j].z * f.x; a1[2] += al[j].z * f.y;
          a0[3] += al[j].w * f.x; a1[3] += al[j].w * f.y;
        }
      }
    } else {
      const __half* xb = xin + l32;
      for (int e0 = 0; e0 < cntR; e0 += 4){
        float4 al[4]; int sv[4]; __half hv[4];
        #pragma unroll
        for (int j = 0; j < 4; j++){ al[j] = qap[e0 + j]; sv[j] = qsp[e0 + j]; }
        #pragma unroll
        for (int j = 0; j < 4; j++)
          hv[j] = xb[sv[j] * 32];
        #pragma unroll
        for (int j = 0; j < 4; j++){
          float xv = __half2float(hv[j]);
          a0[0] += al[j].x * xv;
          a0[1] += al[j].y * xv;
          a0[2] += al[j].z * xv;
          a0[3] += al[j].w * xv;
        }
      }
    }
  };

  if (deg <= 32){
    qa[wv][half][l32] = make_float4(ex[0] * dninv[0], ex[1] * dninv[1],
                                    ex[2] * dninv[2], ex[3] * dninv[3]);
    qs[wv][half][l32] = s;
    WAVE_SYNC();
    accum(deg);
  } else {
    for (int base = 0; base < deg; base += 32){
      const int k = base + l32;
      int s2 = 0; float al[4] = {0.f, 0.f, 0.f, 0.f};
      if (k < deg){
        s2 = csr[beg + k];
        float4 sl = reinterpret_cast<const float4*>(s_in)[s2];
        float t[4] = {sl.x, sl.y, sl.z, sl.w};
        #pragma unroll
        for (int i = 0; i < 4; i++){
          float u = t[i] + d4[i]; u = (u >= 0.f) ? u : NEG * u;
          al[i] = __expf(u) * dninv[i];
        }
      }
      qa[wv][half][l32] = make_float4(al[0], al[1], al[2], al[3]);
      qs[wv][half][l32] = s2;
      WAVE_SYNC();
      accum(min(32, deg - base));
      WAVE_SYNC();
    }
  }

  {
    const int r = li;
    if (F == 64){
      #pragma unroll
      for (int h = 0; h < 4; h++){
        __half2 hv = __floats2half2_rn(a0[h], a1[h]);
        *reinterpret_cast<unsigned*>(&z_lds[r][h * 64 + 2 * l32]) =
            *reinterpret_cast<const unsigned*>(&hv);
      }
    } else {
      #pragma unroll
      for (int h = 0; h < 4; h++)
        z_lds[r][h * 32 + l32] = __float2half(a0[h]);
    }
  }
  __syncthreads();

  const int row = lane & 15, kg = lane >> 4;
  if (wv < 4){
    const int nt = wv;
    f32x4 acc = {0.f,0.f,0.f,0.f};
    const f16x8* wp = reinterpret_cast<const f16x8*>(Wpk) + lane;
    #pragma unroll
    for (int ks = 0; ks < ZW / 32; ks++){
      f16x8 af = *reinterpret_cast<const f16x8*>(&z_lds[row][kg * 8 + ks * 32]);
      acc = __builtin_amdgcn_mfma_f32_16x16x32_f16(af, wp[(ks*4+nt)*64], acc, 0,0,0);
    }
    #pragma unroll
    for (int r = 0; r < 4; r++){
      int rr = kg * 4 + r;
      outs[rr][nt * 16 + row] = fmaxf(acc[r] + cbs[nt * 16 + row], 0.f);
    }
  }
  __syncthreads();

  if (tid < 256){
    int nn = tid >> 4, part = tid & 15;
    if (n0 + nn < N){
      int node = pnode[nn];
      const float* o = &outs[nn][part * 4];
      __half2 h0 = __floats2half2_rn(o[0], o[1]);
      __half2 h1 = __floats2half2_rn(o[2], o[3]);
      uint2 u;
      u.x = *reinterpret_cast<const unsigned*>(&h0);
      u.y = *reinterpret_cast<const unsigned*>(&h1);
      *reinterpret_cast<uint2*>(xo + (size_t)node * 64 + part * 4) = u;
    }
  }

  if (wv == 4){
    f32x4 lacc = {0.f,0.f,0.f,0.f};
    const f16x8* pp = reinterpret_cast<const f16x8*>(Ppk) + lane;
    #pragma unroll
    for (int ks = 0; ks < 2; ks++){
      f16x8 af;
      #pragma unroll
      for (int j = 0; j < 8; j++) af[j] = (_Float16)outs[row][ks * 32 + kg * 8 + j];
      lacc = __builtin_amdgcn_mfma_f32_16x16x32_f16(af, pp[ks * 64], lacc, 0,0,0);
    }
    if (row < 8){
      float* dst = (row < 4) ? s_out : d_out_;
      int q = row & 3;
      #pragma unroll
      for (int r = 0; r < 4; r++){
        if (n0 + kg * 4 + r < N){
          int node = pnode[kg * 4 + r];
          dst[node * 4 + q] = lacc[r];
        }
      }
    }
  }
}

// ---------------- layer-3 aggregation (degree-sorted, z to global) ----------------
__global__ __launch_bounds__(256)
void gat_aggregate_z3(const __half* __restrict__ xin, const float* __restrict__ s_log,
                      const float* __restrict__ d_log, const int* __restrict__ off,
                      const unsigned short* __restrict__ csr, const int* __restrict__ perm,
                      __half* __restrict__ z, int N)
{
  __shared__ float4 qa[4][2][32];
  __shared__ int    qs[4][2][32];
  const int wv   = threadIdx.x >> 6;
  const int lane = threadIdx.x & 63;
  const int half = lane >> 5;
  const int l32  = lane & 31;
  const int idx = blockIdx.x * 8 + wv * 2 + half;
  const bool valid = idx < N;
  const int n = valid ? perm[idx] : 0;

  int beg = 0, deg = 0;
  if (valid){ beg = off[n]; deg = off[n + 1] - beg; }

  float d4[4] = {0.f, 0.f, 0.f, 0.f};
  if (valid){
    float4 d4v = reinterpret_cast<const float4*>(d_log)[n];
    d4[0] = d4v.x; d4[1] = d4v.y; d4[2] = d4v.z; d4[3] = d4v.w;
  }

  float den[4], ex[4];
  int s = 0;
  {
    const bool act = valid && (l32 < deg);
    if (act){
      s = csr[beg + l32];
      float4 sl = reinterpret_cast<const float4*>(s_log)[s];
      float t[4] = {sl.x, sl.y, sl.z, sl.w};
      #pragma unroll
      for (int i = 0; i < 4; i++){
        float u = t[i] + d4[i]; u = (u >= 0.f) ? u : NEG * u;
        ex[i] = __expf(u);
      }
    } else {
      #pragma unroll
      for (int i = 0; i < 4; i++) ex[i] = 0.f;
    }
    #pragma unroll
    for (int i = 0; i < 4; i++) den[i] = wsum32(ex[i]);
  }
  for (int base = 32; base < deg; base += 32){
    const int k = base + l32;
    float e2[4] = {0.f, 0.f, 0.f, 0.f};
    if (k < deg){
      int s2 = csr[beg + k];
      float4 sl = reinterpret_cast<const float4*>(s_log)[s2];
      float t[4] = {sl.x, sl.y, sl.z, sl.w};
      #pragma unroll
      for (int i = 0; i < 4; i++){
        float u = t[i] + d4[i]; u = (u >= 0.f) ? u : NEG * u;
        e2[i] = __expf(u);
      }
    }
    #pragma unroll
    for (int i = 0; i < 4; i++) den[i] += wsum32(e2[i]);
  }

  float dninv[4];
  #pragma unroll
  for (int i = 0; i < 4; i++) dninv[i] = 1.f / fmaxf(den[i], 1e-16f);

  float a0[4] = {0.f,0.f,0.f,0.f};
  float a1[4] = {0.f,0.f,0.f,0.f};
  const float4* qap = qa[wv][half];
  const int*    qsp = qs[wv][half];

  auto accum = [&](int cnt){
    int cntR = (cnt + 3) & ~3;
    const __half* xb = xin + 2 * l32;
    for (int e0 = 0; e0 < cntR; e0 += 4){
      float4 al[4]; int sv[4]; unsigned uv[4];
      #pragma unroll
      for (int j = 0; j < 4; j++){ al[j] = qap[e0 + j]; sv[j] = qsp[e0 + j]; }
      #pragma unroll
      for (int j = 0; j < 4; j++)
        uv[j] = *reinterpret_cast<const unsigned*>(xb + sv[j] * 64);
      #pragma unroll
      for (int j = 0; j < 4; j++){
        float2 f = __half22float2(*reinterpret_cast<const __half2*>(&uv[j]));
        a0[0] += al[j].x * f.x; a1[0] += al[j].x * f.y;
        a0[1] += al[j].y * f.x; a1[1] += al[j].y * f.y;
        a0[2] += al[j].z * f.x; a1[2] += al[j].z * f.y;
        a0[3] += al[j].w * f.x; a1[3] += al[j].w * f.y;
      }
    }
  };

  if (deg <= 32){
    qa[wv][half][l32] = make_float4(ex[0] * dninv[0], ex[1] * dninv[1],
                                    ex[2] * dninv[2], ex[3] * dninv[3]);
    qs[wv][half][l32] = s;
    WAVE_SYNC();
    accum(deg);
  } else {
    for (int base = 0; base < deg; base += 32){
      const int k = base + l32;
      int s2 = 0; float al[4] = {0.f, 0.f, 0.f, 0.f};
      if (k < deg){
        s2 = csr[beg + k];
        float4 sl = reinterpret_cast<const float4*>(s_log)[s2];
        float t[4] = {sl.x, sl.y, sl.z, sl.w};
        #pragma unroll
        for (int i = 0; i < 4; i++){
          float u = t[i] + d4[i]; u = (u >= 0.f) ? u : NEG * u;
          al[i] = __expf(u) * dninv[i];
        }
      }
      qa[wv][half][l32] = make_float4(al[0], al[1], al[2], al[3]);
      qs[wv][half][l32] = s2;
      WAVE_SYNC();
      accum(min(32, deg - base));
      WAVE_SYNC();
    }
  }

  if (valid){
    const size_t zb = (size_t)n * 256 + 2 * l32;
    #pragma unroll
    for (int h = 0; h < 4; h++){
      __half2 hv = __floats2half2_rn(a0[h], a1[h]);
      *reinterpret_cast<unsigned*>(z + zb + h * 64) =
          *reinterpret_cast<const unsigned*>(&hv);
    }
  }
}

// ---------------- pooling (4-way split) + MLP head ----------------
__global__ __launch_bounds__(256)
void pool_partial(const __half* __restrict__ z3, const int* __restrict__ bnd,
                  float* __restrict__ psum)
{
  const int blk = blockIdx.x, tid = threadIdx.x;
  const int g = blk >> 2, part = blk & 3;
  const int s = bnd[g], e = bnd[g + 1];
  const int cp = tid & 127, rp = tid >> 7;
  float ax = 0.f, ay = 0.f;
  for (int n = s + part + 4 * rp; n < e; n += 8){
    __half2 hv = *reinterpret_cast<const __half2*>(z3 + (size_t)n * 256 + 2 * cp);
    float2 f = __half22float2(hv);
    ax += f.x; ay += f.y;
  }
  __shared__ float shx[2][128], shy[2][128];
  shx[rp][cp] = ax; shy[rp][cp] = ay;
  __syncthreads();
  if (tid < 128){
    psum[(size_t)blk * 256 + 2 * tid]     = shx[0][tid] + shx[1][tid];
    psum[(size_t)blk * 256 + 2 * tid + 1] = shy[0][tid] + shy[1][tid];
  }
}

__global__ __launch_bounds__(256)
void head_mlp(const float* __restrict__ psum, const int* __restrict__ bnd,
              const float* __restrict__ Wcp3, const float* __restrict__ cb3,
              const float* __restrict__ m1w, const float* __restrict__ m1b,
              const float* __restrict__ m2w, const float* __restrict__ m2b,
              float* __restrict__ out)
{
  const int g = blockIdx.x, tid = threadIdx.x;
  const float cnt = (float)max(bnd[g + 1] - bnd[g], 1);
  __shared__ float zbar[256];
  const float* pb = psum + (size_t)g * 1024;
  zbar[tid] = (pb[tid] + pb[256 + tid] + pb[512 + tid] + pb[768 + tid]) / cnt;
  __syncthreads();
  const int c = tid & 63, part = tid >> 6;
  float tp = 0.f;
  #pragma unroll 8
  for (int k = part * 64; k < part * 64 + 64; k++) tp += zbar[k] * Wcp3[k * 64 + c];
  __shared__ float tsh[4][64];
  tsh[part][c] = tp;
  __syncthreads();
  __shared__ float tvec[64];
  if (tid < 64)
    tvec[tid] = tsh[0][tid] + tsh[1][tid] + tsh[2][tid] + tsh[3][tid] + cb3[tid];
  __syncthreads();
  float a = m1b[tid];
  #pragma unroll 8
  for (int cc = 0; cc < 64; cc++) a += tvec[cc] * m1w[cc * 256 + tid];
  __shared__ float g1row[256];
  g1row[tid] = fmaxf(a, 0.f);
  __syncthreads();
  float o = m2b[tid];
  #pragma unroll 8
  for (int k = 0; k < 256; k++) o += g1row[k] * m2w[k * 256 + tid];
  out[g * 256 + tid] = o;
}

// ---------------- launcher ----------------
extern "C" void kernel_launch(void* const* d_in, const int* in_sizes, int n_in,
                              void* d_out, int out_size, void* d_ws, size_t ws_size,
                              hipStream_t stream)
{
  const float* x     = (const float*)d_in[0];
  const int*   ei    = (const int*)d_in[1];
  const int*   batch = (const int*)d_in[2];
  const float* W1  = (const float*)d_in[4];
  const float* a1s = (const float*)d_in[5];
  const float* a1d = (const float*)d_in[6];
  const float* b1  = (const float*)d_in[7];
  const float* h1w = (const float*)d_in[8];
  const float* h1b = (const float*)d_in[9];
  const float* W2  = (const float*)d_in[10];
  const float* a2s = (const float*)d_in[11];
  const float* a2d = (const float*)d_in[12];
  const float* b2  = (const float*)d_in[13];
  const float* h2w = (const float*)d_in[14];
  const float* h2b = (const float*)d_in[15];
  const float* W3  = (const float*)d_in[16];
  const float* a3s = (const float*)d_in[17];
  const float* a3d = (const float*)d_in[18];
  const float* b3  = (const float*)d_in[19];
  const float* h3w = (const float*)d_in[20];
  const float* h3b = (const float*)d_in[21];
  const float* m1w = (const float*)d_in[22];
  const float* m1b = (const float*)d_in[23];
  const float* m2w = (const float*)d_in[24];
  const float* m2b = (const float*)d_in[25];

  const int N = in_sizes[0] / 32;
  const int E = in_sizes[1] / 2;
  const int G = out_size / 256;
  const int Etot = E + N;
  const int nbuck = (N + 255) >> 8;

  char* p = (char*)d_ws;
  auto alloc = [&](size_t bytes) -> void* {
    void* r = (void*)p;
    p += ((bytes + 255) / 256) * 256;
    return r;
  };
  __half* zbuf   = (__half*)alloc((size_t)N * GHC * 2);
  __half* xh0    = (__half*)alloc((size_t)N * 32 * 2);
  __half* xh1    = (__half*)alloc((size_t)N * CH * 2);
  __half* xh2    = (__half*)alloc((size_t)N * CH * 2);
  float* s_logA  = (float*)alloc((size_t)N * HD * 4);
  float* d_logA  = (float*)alloc((size_t)N * HD * 4);
  float* s_logB  = (float*)alloc((size_t)N * HD * 4);
  float* d_logB  = (float*)alloc((size_t)N * HD * 4);
  int*   offs    = (int*)alloc((size_t)(N + 1) * 4);
  int*   perm    = (int*)alloc((size_t)N * 4);
  unsigned short* csr = (unsigned short*)alloc((size_t)Etot * 2);
  unsigned* pairs = (unsigned*)alloc((size_t)nbuck * BCAP * 4);
  // contiguous zero-init: bres(1K) Ppk2(2K) Ppk3(2K) ghist(1K) gbincnt(1K)
  int*    bres   = (int*)alloc(256 * 4);
  __half* Ppk2   = (__half*)alloc(1024 * 2);
  __half* Ppk3   = (__half*)alloc(1024 * 2);
  int*    ghist  = (int*)alloc(256 * 4);
  int*    gbincnt= (int*)alloc(256 * 4);
  int*   bnd     = (int*)alloc((size_t)(G + 1) * 4);
  float* psum    = (float*)alloc((size_t)G * 4 * 256 * 4);
  float* Wcp3    = (float*)alloc(256 * 64 * 4);
  float* Psd1    = (float*)alloc(32 * 8 * 4);
  float* cb1     = (float*)alloc(64 * 4);
  float* cb2     = (float*)alloc(64 * 4);
  float* cb3     = (float*)alloc(64 * 4);
  __half* Wpk1   = (__half*)alloc(128 * 64 * 2);
  __half* Wpk2   = (__half*)alloc(256 * 64 * 2);

  hipMemsetAsync(bres, 0, 7168, stream);   // bres + Ppk2 + Ppk3 + ghist + gbincnt

  const int cb_blocks = (Etot + CHUNK - 1) / CHUNK;
  bin_stage<<<cb_blocks, 256, 0, stream>>>(ei, E, N, bres, pairs);
  build_csr<<<nbuck, 256, 0, stream>>>(pairs, bres, N, Etot, offs, csr, ghist);
  perm_scatter<<<nbuck, 256, 0, stream>>>(offs, ghist, gbincnt, perm, N);

  const int fb = 163 + (G + 256) / 256;
  fuse_all<<<fb, 256, 0, stream>>>(W1, a1s, a1d, b1, h1w, h1b,
                                   W2, a2s, a2d, b2, h2w, h2b,
                                   W3, a3s, a3d, b3, h3w, h3b,
                                   Wpk1, Psd1, cb1, Wpk2, Ppk2, cb2, Wcp3, Ppk3, cb3,
                                   batch, N, G, bnd);

  logits_from_x<<<((size_t)N * 8 + 255) / 256, 256, 0, stream>>>(x, Psd1, s_logA, d_logA, xh0, N);

  const int fgrid = (N + 15) / 16;
  gat_layer_fused<32, 128><<<fgrid, 512, 0, stream>>>(xh0, s_logA, d_logA, offs, csr, perm,
                                                      Wpk1, cb1, Ppk2, xh1, s_logB, d_logB, N);
  gat_layer_fused<64, 256><<<fgrid, 512, 0, stream>>>(xh1, s_logB, d_logB, offs, csr, perm,
                                                      Wpk2, cb2, Ppk3, xh2, s_logA, d_logA, N);

  const int ab = (N + 7) / 8;
  gat_aggregate_z3<<<ab, 256, 0, stream>>>(xh2, s_logA, d_logA, offs, csr, perm, zbuf, N);

  pool_partial<<<G * 4, 256, 0, stream>>>(zbuf, bnd, psum);
  head_mlp<<<G, 256, 0, stream>>>(psum, bnd, Wcp3, cb3, m1w, m1b, m2w, m2b, (float*)d_out);
}

// Round 22
// 161.670 us; speedup vs baseline: 2.7668x; 1.0825x over previous
//
#include <hip/hip_runtime.h>
#include <hip/hip_bf16.h>
#include <hip/hip_fp16.h>
#include <math.h>

#define HD 4
#define CH 64
#define GHC 256
#define NEG 0.2f
#define CHUNK 4096
#define BCAP 16384

#define WAVE_SYNC() do { __builtin_amdgcn_wave_barrier(); \
                         asm volatile("s_waitcnt lgkmcnt(0)" ::: "memory"); } while (0)

typedef _Float16 f16x8 __attribute__((ext_vector_type(8)));
typedef float f32x4 __attribute__((ext_vector_type(4)));

__device__ __forceinline__ float wsum32(float v){
  #pragma unroll
  for (int o = 16; o > 0; o >>= 1) v += __shfl_xor(v, o);
  return v;
}

// ---------------- CSR build (bucket-based, 2 kernels) ----------------
__global__ __launch_bounds__(256)
void bin_stage(const int* __restrict__ ei, int E, int N,
               int* __restrict__ bres, unsigned* __restrict__ pairs)
{
  __shared__ unsigned staged[CHUNK];
  __shared__ unsigned short bkt[CHUNK];
  __shared__ int cnts[256], loff[256], gpos[256];
  const int t = threadIdx.x;
  const int tot = E + N;
  const int cbase = blockIdx.x * CHUNK;
  if (cbase >= tot) return;

  cnts[t] = 0;
  __syncthreads();

  unsigned myp[CHUNK / 256];
  int myb[CHUNK / 256], myr[CHUNK / 256];
  #pragma unroll
  for (int j = 0; j < CHUNK / 256; j++){
    int i = cbase + t + j * 256;
    myb[j] = -1;
    if (i < tot){
      int src, dst;
      if (i < E){ src = ei[i]; dst = ei[E + i]; }
      else { src = dst = i - E; }
      myb[j] = dst >> 8;
      myp[j] = (unsigned)src | ((unsigned)dst << 16);
      myr[j] = atomicAdd(&cnts[myb[j]], 1);
    }
  }
  __syncthreads();

  int v = cnts[t];
  loff[t] = v;
  __syncthreads();
  for (int o = 1; o < 256; o <<= 1){
    int tv = (t >= o) ? loff[t - o] : 0;
    __syncthreads();
    loff[t] += tv;
    __syncthreads();
  }
  int excl = loff[t] - v;
  __syncthreads();
  loff[t] = excl;
  __syncthreads();

  #pragma unroll
  for (int j = 0; j < CHUNK / 256; j++){
    if (myb[j] >= 0){
      int slot = loff[myb[j]] + myr[j];
      staged[slot] = myp[j];
      bkt[slot] = (unsigned short)myb[j];
    }
  }
  if (v > 0) gpos[t] = atomicAdd(&bres[t], v);
  __syncthreads();

  int total = min(CHUNK, tot - cbase);
  for (int i = t; i < total; i += 256){
    int b = bkt[i];
    int addr = b * BCAP + gpos[b] + (i - loff[b]);
    pairs[addr] = staged[i];
  }
}

__global__ __launch_bounds__(256)
void build_csr(const unsigned* __restrict__ pairs, const int* __restrict__ bres,
               int N, int Etot, int* __restrict__ offs, unsigned short* __restrict__ csr)
{
  __shared__ int dcnt[256], doff[256], bscan[256];
  const int b = blockIdx.x, t = threadIdx.x;
  int bv = bres[t];
  bscan[t] = bv;
  __syncthreads();
  for (int o = 1; o < 256; o <<= 1){
    int tv = (t >= o) ? bscan[t - o] : 0;
    __syncthreads();
    bscan[t] += tv;
    __syncthreads();
  }
  const int beg = bscan[b] - bres[b];
  const int cnt = bres[b];
  const unsigned* pb = pairs + (size_t)b * BCAP;
  dcnt[t] = 0;
  __syncthreads();
  for (int i = t; i < cnt; i += 256)
    atomicAdd(&dcnt[(pb[i] >> 16) & 255], 1);
  __syncthreads();
  int v = dcnt[t];
  doff[t] = v;
  __syncthreads();
  for (int o = 1; o < 256; o <<= 1){
    int tv = (t >= o) ? doff[t - o] : 0;
    __syncthreads();
    doff[t] += tv;
    __syncthreads();
  }
  int excl = doff[t] - v;
  __syncthreads();
  doff[t] = excl;
  __syncthreads();
  int node = (b << 8) + t;
  if (node < N) offs[node] = beg + doff[t];
  if (b == 0 && t == 0) offs[N] = Etot;
  dcnt[t] = 0;
  __syncthreads();
  for (int i = t; i < cnt; i += 256){
    unsigned pr = pb[i];
    int l = (pr >> 16) & 255;
    int pos = beg + doff[l] + atomicAdd(&dcnt[l], 1);
    csr[pos] = (unsigned short)(pr & 0xFFFF);
  }
}

// ---------------- fused-weight precompute + MFMA packing + graph bounds ----------------
__global__ __launch_bounds__(256)
void fuse_all(const float* __restrict__ W1, const float* __restrict__ a1s,
              const float* __restrict__ a1d, const float* __restrict__ b1,
              const float* __restrict__ h1w, const float* __restrict__ h1b,
              const float* __restrict__ W2, const float* __restrict__ a2s,
              const float* __restrict__ a2d, const float* __restrict__ b2,
              const float* __restrict__ h2w, const float* __restrict__ h2b,
              const float* __restrict__ W3, const float* __restrict__ a3s,
              const float* __restrict__ a3d, const float* __restrict__ b3,
              const float* __restrict__ h3w, const float* __restrict__ h3b,
              __half* __restrict__ Wpk1, float* __restrict__ Psd1, float* __restrict__ cb1,
              __half* __restrict__ Wpk2, __half* __restrict__ Ppk2, float* __restrict__ cb2,
              float* __restrict__ Wcp3, __half* __restrict__ Ppk3, float* __restrict__ cb3,
              const int* __restrict__ batch, int N, int G, int* __restrict__ bnd)
{
  const int blk = blockIdx.x, t = threadIdx.x;
  if (blk >= 163){
    int g = (blk - 163) * 256 + t;
    if (g > G) return;
    if (g == G){ bnd[G] = N; return; }
    int lo = 0, hi = N;
    while (lo < hi){ int mid = (lo + hi) >> 1; if (batch[mid] < g) lo = mid + 1; else hi = mid; }
    bnd[g] = lo;
    return;
  }
  const float *W, *as, *ad, *bl, *hlw, *hlb;
  float *cb;
  int FIN, b, layer;
  if (blk < 33){
    W = W1; as = a1s; ad = a1d; bl = b1; hlw = h1w; hlb = h1b;
    cb = cb1; FIN = 32; b = blk; layer = 1;
  } else if (blk < 98){
    W = W2; as = a2s; ad = a2d; bl = b2; hlw = h2w; hlb = h2b;
    cb = cb2; FIN = 64; b = blk - 33; layer = 2;
  } else {
    W = W3; as = a3s; ad = a3d; bl = b3; hlw = h3w; hlb = h3b;
    cb = cb3; FIN = 64; b = blk - 98; layer = 3;
  }
  if (b < FIN){
    const int c = t >> 2, h = t & 3;
    const float* wrow = W + b * GHC + h * 64;
    float acc = 0.f;
    #pragma unroll 8
    for (int j = 0; j < 64; j++)
      acc += wrow[j] * hlw[(h * 64 + j) * CH + c];
    const int k = h * FIN + b;
    if (layer == 3){
      Wcp3[k * CH + c] = acc;
    } else {
      int ks = k >> 5, nt = c >> 4;
      int lane = (((k & 31) >> 3) << 4) | (c & 15);
      int idx = ((ks * 4 + nt) * 64 + lane) * 8 + (k & 7);
      __half* Wpk = (layer == 1) ? Wpk1 : Wpk2;
      Wpk[idx] = __float2half(acc);
    }
    if (t < 8){
      const int hh = t & 3;
      const float* a = (t < 4) ? as : ad;
      const float* wr2 = W + b * GHC + hh * 64;
      float p = 0.f;
      #pragma unroll 8
      for (int j = 0; j < 64; j++) p += wr2[j] * a[hh * 64 + j];
      if (layer == 1){
        Psd1[b * 8 + t] = p;
      } else {
        int kk = b;
        int ks = kk >> 5;
        int lane = (((kk & 31) >> 3) << 4) | t;
        int idx = (ks * 64 + lane) * 8 + (kk & 7);
        __half* Ppk = (layer == 2) ? Ppk2 : Ppk3;
        Ppk[idx] = __float2half(p);
      }
    }
  } else if (t < CH){
    float acc = hlb[t];
    for (int j = 0; j < GHC; j++) acc += bl[j] * hlw[j * CH + t];
    cb[t] = acc;
  }
}

// ---------------- layer-1 logits from raw x + fp16 cast of x ----------------
__global__ __launch_bounds__(256)
void logits_from_x(const float* __restrict__ x, const float* __restrict__ Psd,
                   float* __restrict__ s_log, float* __restrict__ d_log,
                   __half* __restrict__ xh0, int N)
{
  int idx = blockIdx.x * 256 + threadIdx.x;
  int node = idx >> 3, q = idx & 7;
  if (node >= N) return;
  const float* xr = x + (size_t)node * 32;
  float v = 0.f;
  #pragma unroll 8
  for (int k = 0; k < 32; k++) v += xr[k] * Psd[k * 8 + q];
  if (q < 4){
    s_log[node * 4 + q] = v;
    __half2 h0 = __floats2half2_rn(xr[q*8+0], xr[q*8+1]);
    __half2 h1 = __floats2half2_rn(xr[q*8+2], xr[q*8+3]);
    __half2 h2 = __floats2half2_rn(xr[q*8+4], xr[q*8+5]);
    __half2 h3 = __floats2half2_rn(xr[q*8+6], xr[q*8+7]);
    uint4 u;
    u.x = *reinterpret_cast<const unsigned*>(&h0);
    u.y = *reinterpret_cast<const unsigned*>(&h1);
    u.z = *reinterpret_cast<const unsigned*>(&h2);
    u.w = *reinterpret_cast<const unsigned*>(&h3);
    *reinterpret_cast<uint4*>(xh0 + (size_t)node * 32 + q * 8) = u;
  } else {
    d_log[node * 4 + (q - 4)] = v;
  }
}

// ================= fused layer: aggregate (LDS z) + MFMA transform =================
template<int F, int ZW>
__global__ __launch_bounds__(512)
void gat_layer_fused(const __half* __restrict__ xin, const float* __restrict__ s_in,
                     const float* __restrict__ d_in_, const int* __restrict__ off,
                     const unsigned short* __restrict__ csr,
                     const __half* __restrict__ Wpk, const float* __restrict__ cb,
                     const __half* __restrict__ Ppk,
                     __half* __restrict__ xo, float* __restrict__ s_out,
                     float* __restrict__ d_out_, int N)
{
  constexpr int ZP = ZW + 8;
  __shared__ float4 qa[8][2][32];
  __shared__ int    qs[8][2][32];
  __shared__ __half z_lds[16][ZP];
  __shared__ float  outs[16][68];
  __shared__ float  cbs[64];
  const int tid  = threadIdx.x;
  const int wv   = tid >> 6;
  const int lane = tid & 63;
  const int half = lane >> 5;
  const int l32  = lane & 31;
  const int n0 = blockIdx.x * 16;
  const int n = n0 + wv * 2 + half;
  const bool valid = n < N;
  if (tid < 64) cbs[tid] = cb[tid];

  int beg = 0, deg = 0;
  if (valid){ beg = off[n]; deg = off[n + 1] - beg; }

  float d4[4] = {0.f, 0.f, 0.f, 0.f};
  if (valid){
    float4 d4v = reinterpret_cast<const float4*>(d_in_)[n];
    d4[0] = d4v.x; d4[1] = d4v.y; d4[2] = d4v.z; d4[3] = d4v.w;
  }

  float den[4], ex[4];
  int s = 0;
  {
    const bool act = valid && (l32 < deg);
    if (act){
      s = csr[beg + l32];
      float4 sl = reinterpret_cast<const float4*>(s_in)[s];
      float t[4] = {sl.x, sl.y, sl.z, sl.w};
      #pragma unroll
      for (int i = 0; i < 4; i++){
        float u = t[i] + d4[i]; u = (u >= 0.f) ? u : NEG * u;
        ex[i] = __expf(u);
      }
    } else {
      #pragma unroll
      for (int i = 0; i < 4; i++) ex[i] = 0.f;
    }
    #pragma unroll
    for (int i = 0; i < 4; i++) den[i] = wsum32(ex[i]);
  }
  for (int base = 32; base < deg; base += 32){
    const int k = base + l32;
    float e2[4] = {0.f, 0.f, 0.f, 0.f};
    if (k < deg){
      int s2 = csr[beg + k];
      float4 sl = reinterpret_cast<const float4*>(s_in)[s2];
      float t[4] = {sl.x, sl.y, sl.z, sl.w};
      #pragma unroll
      for (int i = 0; i < 4; i++){
        float u = t[i] + d4[i]; u = (u >= 0.f) ? u : NEG * u;
        e2[i] = __expf(u);
      }
    }
    #pragma unroll
    for (int i = 0; i < 4; i++) den[i] += wsum32(e2[i]);
  }

  float dninv[4];
  #pragma unroll
  for (int i = 0; i < 4; i++) dninv[i] = 1.f / fmaxf(den[i], 1e-16f);

  float a0[4] = {0.f,0.f,0.f,0.f};
  float a1[4] = {0.f,0.f,0.f,0.f};
  const float4* qap = qa[wv][half];
  const int*    qsp = qs[wv][half];

  auto accum = [&](int cnt){
    int cntR = (cnt + 3) & ~3;
    if (F == 64){
      const __half* xb = xin + 2 * l32;
      for (int e0 = 0; e0 < cntR; e0 += 4){
        float4 al[4]; int sv[4]; unsigned uv[4];
        #pragma unroll
        for (int j = 0; j < 4; j++){ al[j] = qap[e0 + j]; sv[j] = qsp[e0 + j]; }
        #pragma unroll
        for (int j = 0; j < 4; j++)
          uv[j] = *reinterpret_cast<const unsigned*>(xb + sv[j] * 64);
        #pragma unroll
        for (int j = 0; j < 4; j++){
          float2 f = __half22float2(*reinterpret_cast<const __half2*>(&uv[j]));
          a0[0] += al[j].x * f.x; a1[0] += al[j].x * f.y;
          a0[1] += al[j].y * f.x; a1[1] += al[j].y * f.y;
          a0[2] += al[j].z * f.x; a1[2] += al[j].z * f.y;
          a0[3] += al[j].w * f.x; a1[3] += al[j].w * f.y;
        }
      }
    } else {
      const __half* xb = xin + l32;
      for (int e0 = 0; e0 < cntR; e0 += 4){
        float4 al[4]; int sv[4]; __half hv[4];
        #pragma unroll
        for (int j = 0; j < 4; j++){ al[j] = qap[e0 + j]; sv[j] = qsp[e0 + j]; }
        #pragma unroll
        for (int j = 0; j < 4; j++)
          hv[j] = xb[sv[j] * 32];
        #pragma unroll
        for (int j = 0; j < 4; j++){
          float xv = __half2float(hv[j]);
          a0[0] += al[j].x * xv;
          a0[1] += al[j].y * xv;
          a0[2] += al[j].z * xv;
          a0[3] += al[j].w * xv;
        }
      }
    }
  };

  if (deg <= 32){
    qa[wv][half][l32] = make_float4(ex[0] * dninv[0], ex[1] * dninv[1],
                                    ex[2] * dninv[2], ex[3] * dninv[3]);
    qs[wv][half][l32] = s;
    WAVE_SYNC();
    accum(deg);
  } else {
    for (int base = 0; base < deg; base += 32){
      const int k = base + l32;
      int s2 = 0; float al[4] = {0.f, 0.f, 0.f, 0.f};
      if (k < deg){
        s2 = csr[beg + k];
        float4 sl = reinterpret_cast<const float4*>(s_in)[s2];
        float t[4] = {sl.x, sl.y, sl.z, sl.w};
        #pragma unroll
        for (int i = 0; i < 4; i++){
          float u = t[i] + d4[i]; u = (u >= 0.f) ? u : NEG * u;
          al[i] = __expf(u) * dninv[i];
        }
      }
      qa[wv][half][l32] = make_float4(al[0], al[1], al[2], al[3]);
      qs[wv][half][l32] = s2;
      WAVE_SYNC();
      accum(min(32, deg - base));
      WAVE_SYNC();
    }
  }

  {
    const int r = wv * 2 + half;
    if (F == 64){
      #pragma unroll
      for (int h = 0; h < 4; h++){
        __half2 hv = __floats2half2_rn(a0[h], a1[h]);
        *reinterpret_cast<unsigned*>(&z_lds[r][h * 64 + 2 * l32]) =
            *reinterpret_cast<const unsigned*>(&hv);
      }
    } else {
      #pragma unroll
      for (int h = 0; h < 4; h++)
        z_lds[r][h * 32 + l32] = __float2half(a0[h]);
    }
  }
  __syncthreads();

  const int row = lane & 15, kg = lane >> 4;
  if (wv < 4){
    const int nt = wv;
    f32x4 acc = {0.f,0.f,0.f,0.f};
    const f16x8* wp = reinterpret_cast<const f16x8*>(Wpk) + lane;
    #pragma unroll
    for (int ks = 0; ks < ZW / 32; ks++){
      f16x8 af = *reinterpret_cast<const f16x8*>(&z_lds[row][kg * 8 + ks * 32]);
      acc = __builtin_amdgcn_mfma_f32_16x16x32_f16(af, wp[(ks*4+nt)*64], acc, 0,0,0);
    }
    #pragma unroll
    for (int r = 0; r < 4; r++){
      int rr = kg * 4 + r;
      outs[rr][nt * 16 + row] = fmaxf(acc[r] + cbs[nt * 16 + row], 0.f);
    }
  }
  __syncthreads();

  if (tid < 256){
    int nn = tid >> 4, part = tid & 15;
    int node = n0 + nn;
    if (node < N){
      const float* o = &outs[nn][part * 4];
      __half2 h0 = __floats2half2_rn(o[0], o[1]);
      __half2 h1 = __floats2half2_rn(o[2], o[3]);
      uint2 u;
      u.x = *reinterpret_cast<const unsigned*>(&h0);
      u.y = *reinterpret_cast<const unsigned*>(&h1);
      *reinterpret_cast<uint2*>(xo + (size_t)node * 64 + part * 4) = u;
    }
  }

  if (wv == 4){
    f32x4 lacc = {0.f,0.f,0.f,0.f};
    const f16x8* pp = reinterpret_cast<const f16x8*>(Ppk) + lane;
    #pragma unroll
    for (int ks = 0; ks < 2; ks++){
      f16x8 af;
      #pragma unroll
      for (int j = 0; j < 8; j++) af[j] = (_Float16)outs[row][ks * 32 + kg * 8 + j];
      lacc = __builtin_amdgcn_mfma_f32_16x16x32_f16(af, pp[ks * 64], lacc, 0,0,0);
    }
    if (row < 8){
      float* dst = (row < 4) ? s_out : d_out_;
      int q = row & 3;
      #pragma unroll
      for (int r = 0; r < 4; r++){
        int node = n0 + kg * 4 + r;
        if (node < N) dst[node * 4 + q] = lacc[r];
      }
    }
  }
}

// ---------------- layer-3 aggregation (z to global, 256-wide) ----------------
template<int F>
__global__ __launch_bounds__(256)
void gat_aggregate_z(const __half* __restrict__ xin, const float* __restrict__ s_log,
                     const float* __restrict__ d_log, const int* __restrict__ off,
                     const unsigned short* __restrict__ csr, __half* __restrict__ z, int N)
{
  __shared__ float4 qa[4][2][32];
  __shared__ int    qs[4][2][32];
  const int wv   = threadIdx.x >> 6;
  const int lane = threadIdx.x & 63;
  const int half = lane >> 5;
  const int l32  = lane & 31;
  const int n = blockIdx.x * 8 + wv * 2 + half;
  const bool valid = n < N;

  int beg = 0, deg = 0;
  if (valid){ beg = off[n]; deg = off[n + 1] - beg; }

  float d4[4] = {0.f, 0.f, 0.f, 0.f};
  if (valid){
    float4 d4v = reinterpret_cast<const float4*>(d_log)[n];
    d4[0] = d4v.x; d4[1] = d4v.y; d4[2] = d4v.z; d4[3] = d4v.w;
  }

  float den[4], ex[4];
  int s = 0;
  {
    const bool act = valid && (l32 < deg);
    if (act){
      s = csr[beg + l32];
      float4 sl = reinterpret_cast<const float4*>(s_log)[s];
      float t[4] = {sl.x, sl.y, sl.z, sl.w};
      #pragma unroll
      for (int i = 0; i < 4; i++){
        float u = t[i] + d4[i]; u = (u >= 0.f) ? u : NEG * u;
        ex[i] = __expf(u);
      }
    } else {
      #pragma unroll
      for (int i = 0; i < 4; i++) ex[i] = 0.f;
    }
    #pragma unroll
    for (int i = 0; i < 4; i++) den[i] = wsum32(ex[i]);
  }
  for (int base = 32; base < deg; base += 32){
    const int k = base + l32;
    float e2[4] = {0.f, 0.f, 0.f, 0.f};
    if (k < deg){
      int s2 = csr[beg + k];
      float4 sl = reinterpret_cast<const float4*>(s_log)[s2];
      float t[4] = {sl.x, sl.y, sl.z, sl.w};
      #pragma unroll
      for (int i = 0; i < 4; i++){
        float u = t[i] + d4[i]; u = (u >= 0.f) ? u : NEG * u;
        e2[i] = __expf(u);
      }
    }
    #pragma unroll
    for (int i = 0; i < 4; i++) den[i] += wsum32(e2[i]);
  }

  float dninv[4];
  #pragma unroll
  for (int i = 0; i < 4; i++) dninv[i] = 1.f / fmaxf(den[i], 1e-16f);

  float a0[4] = {0.f,0.f,0.f,0.f};
  float a1[4] = {0.f,0.f,0.f,0.f};
  const float4* qap = qa[wv][half];
  const int*    qsp = qs[wv][half];

  auto accum = [&](int cnt){
    int cntR = (cnt + 3) & ~3;
    const __half* xb = xin + 2 * l32;
    for (int e0 = 0; e0 < cntR; e0 += 4){
      float4 al[4]; int sv[4]; unsigned uv[4];
      #pragma unroll
      for (int j = 0; j < 4; j++){ al[j] = qap[e0 + j]; sv[j] = qsp[e0 + j]; }
      #pragma unroll
      for (int j = 0; j < 4; j++)
        uv[j] = *reinterpret_cast<const unsigned*>(xb + sv[j] * 64);
      #pragma unroll
      for (int j = 0; j < 4; j++){
        float2 f = __half22float2(*reinterpret_cast<const __half2*>(&uv[j]));
        a0[0] += al[j].x * f.x; a1[0] += al[j].x * f.y;
        a0[1] += al[j].y * f.x; a1[1] += al[j].y * f.y;
        a0[2] += al[j].z * f.x; a1[2] += al[j].z * f.y;
        a0[3] += al[j].w * f.x; a1[3] += al[j].w * f.y;
      }
    }
  };

  if (deg <= 32){
    qa[wv][half][l32] = make_float4(ex[0] * dninv[0], ex[1] * dninv[1],
                                    ex[2] * dninv[2], ex[3] * dninv[3]);
    qs[wv][half][l32] = s;
    WAVE_SYNC();
    accum(deg);
  } else {
    for (int base = 0; base < deg; base += 32){
      const int k = base + l32;
      int s2 = 0; float al[4] = {0.f, 0.f, 0.f, 0.f};
      if (k < deg){
        s2 = csr[beg + k];
        float4 sl = reinterpret_cast<const float4*>(s_log)[s2];
        float t[4] = {sl.x, sl.y, sl.z, sl.w};
        #pragma unroll
        for (int i = 0; i < 4; i++){
          float u = t[i] + d4[i]; u = (u >= 0.f) ? u : NEG * u;
          al[i] = __expf(u) * dninv[i];
        }
      }
      qa[wv][half][l32] = make_float4(al[0], al[1], al[2], al[3]);
      qs[wv][half][l32] = s2;
      WAVE_SYNC();
      accum(min(32, deg - base));
      WAVE_SYNC();
    }
  }

  if (valid){
    const size_t zb = (size_t)n * 256 + 2 * l32;
    #pragma unroll
    for (int h = 0; h < 4; h++){
      __half2 hv = __floats2half2_rn(a0[h], a1[h]);
      *reinterpret_cast<unsigned*>(z + zb + h * 64) =
          *reinterpret_cast<const unsigned*>(&hv);
    }
  }
}

// ---------------- pooling (4-way split) + MLP head ----------------
__global__ __launch_bounds__(256)
void pool_partial(const __half* __restrict__ z3, const int* __restrict__ bnd,
                  float* __restrict__ psum)
{
  const int blk = blockIdx.x, tid = threadIdx.x;
  const int g = blk >> 2, part = blk & 3;
  const int s = bnd[g], e = bnd[g + 1];
  const int cp = tid & 127, rp = tid >> 7;
  float ax = 0.f, ay = 0.f;
  for (int n = s + part + 4 * rp; n < e; n += 8){
    __half2 hv = *reinterpret_cast<const __half2*>(z3 + (size_t)n * 256 + 2 * cp);
    float2 f = __half22float2(hv);
    ax += f.x; ay += f.y;
  }
  __shared__ float shx[2][128], shy[2][128];
  shx[rp][cp] = ax; shy[rp][cp] = ay;
  __syncthreads();
  if (tid < 128){
    psum[(size_t)blk * 256 + 2 * tid]     = shx[0][tid] + shx[1][tid];
    psum[(size_t)blk * 256 + 2 * tid + 1] = shy[0][tid] + shy[1][tid];
  }
}

__global__ __launch_bounds__(256)
void head_mlp(const float* __restrict__ psum, const int* __restrict__ bnd,
              const float* __restrict__ Wcp3, const float* __restrict__ cb3,
              const float* __restrict__ m1w, const float* __restrict__ m1b,
              const float* __restrict__ m2w, const float* __restrict__ m2b,
              float* __restrict__ out)
{
  const int g = blockIdx.x, tid = threadIdx.x;
  const float cnt = (float)max(bnd[g + 1] - bnd[g], 1);
  __shared__ float zbar[256];
  const float* pb = psum + (size_t)g * 1024;
  zbar[tid] = (pb[tid] + pb[256 + tid] + pb[512 + tid] + pb[768 + tid]) / cnt;
  __syncthreads();
  const int c = tid & 63, part = tid >> 6;
  float tp = 0.f;
  #pragma unroll 8
  for (int k = part * 64; k < part * 64 + 64; k++) tp += zbar[k] * Wcp3[k * 64 + c];
  __shared__ float tsh[4][64];
  tsh[part][c] = tp;
  __syncthreads();
  __shared__ float tvec[64];
  if (tid < 64)
    tvec[tid] = tsh[0][tid] + tsh[1][tid] + tsh[2][tid] + tsh[3][tid] + cb3[tid];
  __syncthreads();
  float a = m1b[tid];
  #pragma unroll 8
  for (int cc = 0; cc < 64; cc++) a += tvec[cc] * m1w[cc * 256 + tid];
  __shared__ float g1row[256];
  g1row[tid] = fmaxf(a, 0.f);
  __syncthreads();
  float o = m2b[tid];
  #pragma unroll 8
  for (int k = 0; k < 256; k++) o += g1row[k] * m2w[k * 256 + tid];
  out[g * 256 + tid] = o;
}

// ---------------- launcher ----------------
extern "C" void kernel_launch(void* const* d_in, const int* in_sizes, int n_in,
                              void* d_out, int out_size, void* d_ws, size_t ws_size,
                              hipStream_t stream)
{
  const float* x     = (const float*)d_in[0];
  const int*   ei    = (const int*)d_in[1];
  const int*   batch = (const int*)d_in[2];
  const float* W1  = (const float*)d_in[4];
  const float* a1s = (const float*)d_in[5];
  const float* a1d = (const float*)d_in[6];
  const float* b1  = (const float*)d_in[7];
  const float* h1w = (const float*)d_in[8];
  const float* h1b = (const float*)d_in[9];
  const float* W2  = (const float*)d_in[10];
  const float* a2s = (const float*)d_in[11];
  const float* a2d = (const float*)d_in[12];
  const float* b2  = (const float*)d_in[13];
  const float* h2w = (const float*)d_in[14];
  const float* h2b = (const float*)d_in[15];
  const float* W3  = (const float*)d_in[16];
  const float* a3s = (const float*)d_in[17];
  const float* a3d = (const float*)d_in[18];
  const float* b3  = (const float*)d_in[19];
  const float* h3w = (const float*)d_in[20];
  const float* h3b = (const float*)d_in[21];
  const float* m1w = (const float*)d_in[22];
  const float* m1b = (const float*)d_in[23];
  const float* m2w = (const float*)d_in[24];
  const float* m2b = (const float*)d_in[25];

  const int N = in_sizes[0] / 32;
  const int E = in_sizes[1] / 2;
  const int G = out_size / 256;
  const int Etot = E + N;
  const int nbuck = (N + 255) >> 8;

  char* p = (char*)d_ws;
  auto alloc = [&](size_t bytes) -> void* {
    void* r = (void*)p;
    p += ((bytes + 255) / 256) * 256;
    return r;
  };
  __half* zbuf   = (__half*)alloc((size_t)N * GHC * 2);
  __half* xh0    = (__half*)alloc((size_t)N * 32 * 2);
  __half* xh1    = (__half*)alloc((size_t)N * CH * 2);
  __half* xh2    = (__half*)alloc((size_t)N * CH * 2);
  float* s_logA  = (float*)alloc((size_t)N * HD * 4);
  float* d_logA  = (float*)alloc((size_t)N * HD * 4);
  float* s_logB  = (float*)alloc((size_t)N * HD * 4);
  float* d_logB  = (float*)alloc((size_t)N * HD * 4);
  int*   offs    = (int*)alloc((size_t)(N + 1) * 4);
  unsigned short* csr = (unsigned short*)alloc((size_t)Etot * 2);
  unsigned* pairs = (unsigned*)alloc((size_t)nbuck * BCAP * 4);
  int*    bres   = (int*)alloc(256 * 4);
  __half* Ppk2   = (__half*)alloc(1024 * 2);
  __half* Ppk3   = (__half*)alloc(1024 * 2);
  int*   bnd     = (int*)alloc((size_t)(G + 1) * 4);
  float* psum    = (float*)alloc((size_t)G * 4 * 256 * 4);
  float* Wcp3    = (float*)alloc(256 * 64 * 4);
  float* Psd1    = (float*)alloc(32 * 8 * 4);
  float* cb1     = (float*)alloc(64 * 4);
  float* cb2     = (float*)alloc(64 * 4);
  float* cb3     = (float*)alloc(64 * 4);
  __half* Wpk1   = (__half*)alloc(128 * 64 * 2);
  __half* Wpk2   = (__half*)alloc(256 * 64 * 2);

  hipMemsetAsync(bres, 0, 5120, stream);   // bres + Ppk2 + Ppk3

  const int cb_blocks = (Etot + CHUNK - 1) / CHUNK;
  bin_stage<<<cb_blocks, 256, 0, stream>>>(ei, E, N, bres, pairs);
  build_csr<<<nbuck, 256, 0, stream>>>(pairs, bres, N, Etot, offs, csr);

  const int fb = 163 + (G + 256) / 256;
  fuse_all<<<fb, 256, 0, stream>>>(W1, a1s, a1d, b1, h1w, h1b,
                                   W2, a2s, a2d, b2, h2w, h2b,
                                   W3, a3s, a3d, b3, h3w, h3b,
                                   Wpk1, Psd1, cb1, Wpk2, Ppk2, cb2, Wcp3, Ppk3, cb3,
                                   batch, N, G, bnd);

  logits_from_x<<<((size_t)N * 8 + 255) / 256, 256, 0, stream>>>(x, Psd1, s_logA, d_logA, xh0, N);

  const int fgrid = (N + 15) / 16;
  gat_layer_fused<32, 128><<<fgrid, 512, 0, stream>>>(xh0, s_logA, d_logA, offs, csr,
                                                      Wpk1, cb1, Ppk2, xh1, s_logB, d_logB, N);
  gat_layer_fused<64, 256><<<fgrid, 512, 0, stream>>>(xh1, s_logB, d_logB, offs, csr,
                                                      Wpk2, cb2, Ppk3, xh2, s_logA, d_logA, N);

  const int ab = (N + 7) / 8;
  gat_aggregate_z<64><<<ab, 256, 0, stream>>>(xh2, s_logA, d_logA, offs, csr, zbuf, N);

  pool_partial<<<G * 4, 256, 0, stream>>>(zbuf, bnd, psum);
  head_mlp<<<G, 256, 0, stream>>>(psum, bnd, Wcp3, cb3, m1w, m1b, m2w, m2b, (float*)d_out);
}

// Round 23
// 150.061 us; speedup vs baseline: 2.9808x; 1.0774x over previous
//
#include <hip/hip_runtime.h>
#include <hip/hip_bf16.h>
#include <hip/hip_fp16.h>
#include <math.h>

#define HD 4
#define CH 64
#define GHC 256
#define NEG 0.2f
#define CHUNK 4096
#define BCAP 16384

#define WAVE_SYNC() do { __builtin_amdgcn_wave_barrier(); \
                         asm volatile("s_waitcnt lgkmcnt(0)" ::: "memory"); } while (0)

typedef _Float16 f16x8 __attribute__((ext_vector_type(8)));
typedef float f32x4 __attribute__((ext_vector_type(4)));

__device__ __forceinline__ float wsum32(float v){
  #pragma unroll
  for (int o = 16; o > 0; o >>= 1) v += __shfl_xor(v, o);
  return v;
}

// ================= front kernel: bin_stage  U  (fuse_all + graph_bounds) =================
__global__ __launch_bounds__(256)
void front_kernel(const int* __restrict__ ei, int E, int N, int cb_blocks,
                  int* __restrict__ bres, unsigned* __restrict__ pairs,
                  const float* __restrict__ W1, const float* __restrict__ a1s,
                  const float* __restrict__ a1d, const float* __restrict__ b1,
                  const float* __restrict__ h1w, const float* __restrict__ h1b,
                  const float* __restrict__ W2, const float* __restrict__ a2s,
                  const float* __restrict__ a2d, const float* __restrict__ b2,
                  const float* __restrict__ h2w, const float* __restrict__ h2b,
                  const float* __restrict__ W3, const float* __restrict__ a3s,
                  const float* __restrict__ a3d, const float* __restrict__ b3,
                  const float* __restrict__ h3w, const float* __restrict__ h3b,
                  __half* __restrict__ Wpk1, float* __restrict__ Psd1, float* __restrict__ cb1,
                  __half* __restrict__ Wpk2, __half* __restrict__ Ppk2, float* __restrict__ cb2,
                  float* __restrict__ Wcp3, __half* __restrict__ Ppk3, float* __restrict__ cb3,
                  const int* __restrict__ batch, int G, int* __restrict__ bnd)
{
  __shared__ unsigned staged[CHUNK];
  __shared__ unsigned short bkt[CHUNK];
  __shared__ int cnts[256], loff[256], gpos[256];
  const int t = threadIdx.x;

  if (blockIdx.x < cb_blocks){
    // ---------- bin_stage ----------
    const int tot = E + N;
    const int cbase = blockIdx.x * CHUNK;
    if (cbase >= tot) return;

    cnts[t] = 0;
    __syncthreads();

    unsigned myp[CHUNK / 256];
    int myb[CHUNK / 256], myr[CHUNK / 256];
    #pragma unroll
    for (int j = 0; j < CHUNK / 256; j++){
      int i = cbase + t + j * 256;
      myb[j] = -1;
      if (i < tot){
        int src, dst;
        if (i < E){ src = ei[i]; dst = ei[E + i]; }
        else { src = dst = i - E; }
        myb[j] = dst >> 8;
        myp[j] = (unsigned)src | ((unsigned)dst << 16);
        myr[j] = atomicAdd(&cnts[myb[j]], 1);
      }
    }
    __syncthreads();

    int v = cnts[t];
    loff[t] = v;
    __syncthreads();
    for (int o = 1; o < 256; o <<= 1){
      int tv = (t >= o) ? loff[t - o] : 0;
      __syncthreads();
      loff[t] += tv;
      __syncthreads();
    }
    int excl = loff[t] - v;
    __syncthreads();
    loff[t] = excl;
    __syncthreads();

    #pragma unroll
    for (int j = 0; j < CHUNK / 256; j++){
      if (myb[j] >= 0){
        int slot = loff[myb[j]] + myr[j];
        staged[slot] = myp[j];
        bkt[slot] = (unsigned short)myb[j];
      }
    }
    if (v > 0) gpos[t] = atomicAdd(&bres[t], v);
    __syncthreads();

    int total = min(CHUNK, tot - cbase);
    for (int i = t; i < total; i += 256){
      int b = bkt[i];
      int addr = b * BCAP + gpos[b] + (i - loff[b]);
      pairs[addr] = staged[i];
    }
    return;
  }

  // ---------- fuse_all + graph_bounds ----------
  const int blk = blockIdx.x - cb_blocks;
  if (blk >= 163){
    int g = (blk - 163) * 256 + t;
    if (g > G) return;
    if (g == G){ bnd[G] = N; return; }
    int lo = 0, hi = N;
    while (lo < hi){ int mid = (lo + hi) >> 1; if (batch[mid] < g) lo = mid + 1; else hi = mid; }
    bnd[g] = lo;
    return;
  }
  const float *W, *as, *ad, *bl, *hlw, *hlb;
  float *cb;
  int FIN, b, layer;
  if (blk < 33){
    W = W1; as = a1s; ad = a1d; bl = b1; hlw = h1w; hlb = h1b;
    cb = cb1; FIN = 32; b = blk; layer = 1;
  } else if (blk < 98){
    W = W2; as = a2s; ad = a2d; bl = b2; hlw = h2w; hlb = h2b;
    cb = cb2; FIN = 64; b = blk - 33; layer = 2;
  } else {
    W = W3; as = a3s; ad = a3d; bl = b3; hlw = h3w; hlb = h3b;
    cb = cb3; FIN = 64; b = blk - 98; layer = 3;
  }
  if (b < FIN){
    const int c = t >> 2, h = t & 3;
    const float* wrow = W + b * GHC + h * 64;
    float acc = 0.f;
    #pragma unroll 8
    for (int j = 0; j < 64; j++)
      acc += wrow[j] * hlw[(h * 64 + j) * CH + c];
    const int k = h * FIN + b;
    if (layer == 3){
      Wcp3[k * CH + c] = acc;
    } else {
      int ks = k >> 5, nt = c >> 4;
      int lane = (((k & 31) >> 3) << 4) | (c & 15);
      int idx = ((ks * 4 + nt) * 64 + lane) * 8 + (k & 7);
      __half* Wpk = (layer == 1) ? Wpk1 : Wpk2;
      Wpk[idx] = __float2half(acc);
    }
    if (t < 8){
      const int hh = t & 3;
      const float* a = (t < 4) ? as : ad;
      const float* wr2 = W + b * GHC + hh * 64;
      float p = 0.f;
      #pragma unroll 8
      for (int j = 0; j < 64; j++) p += wr2[j] * a[hh * 64 + j];
      if (layer == 1){
        Psd1[b * 8 + t] = p;
      } else {
        int kk = b;
        int ks = kk >> 5;
        int lane = (((kk & 31) >> 3) << 4) | t;
        int idx = (ks * 64 + lane) * 8 + (kk & 7);
        __half* Ppk = (layer == 2) ? Ppk2 : Ppk3;
        Ppk[idx] = __float2half(p);
      }
    }
  } else if (t < CH){
    float acc = hlb[t];
    for (int j = 0; j < GHC; j++) acc += bl[j] * hlw[j * CH + t];
    cb[t] = acc;
  }
}

// ================= mid kernel: build_csr  U  logits_from_x =================
__global__ __launch_bounds__(256)
void mid_kernel(const unsigned* __restrict__ pairs, const int* __restrict__ bres,
                int N, int Etot, int nbuck,
                int* __restrict__ offs, unsigned short* __restrict__ csr,
                const float* __restrict__ x, const float* __restrict__ Psd,
                float* __restrict__ s_log, float* __restrict__ d_log,
                __half* __restrict__ xh0)
{
  __shared__ int dcnt[256], doff[256], bscan[256];
  const int t = threadIdx.x;

  if (blockIdx.x < nbuck){
    // ---------- build_csr ----------
    const int b = blockIdx.x;
    int bv = bres[t];
    bscan[t] = bv;
    __syncthreads();
    for (int o = 1; o < 256; o <<= 1){
      int tv = (t >= o) ? bscan[t - o] : 0;
      __syncthreads();
      bscan[t] += tv;
      __syncthreads();
    }
    const int beg = bscan[b] - bres[b];
    const int cnt = bres[b];
    const unsigned* pb = pairs + (size_t)b * BCAP;
    dcnt[t] = 0;
    __syncthreads();
    for (int i = t; i < cnt; i += 256)
      atomicAdd(&dcnt[(pb[i] >> 16) & 255], 1);
    __syncthreads();
    int v = dcnt[t];
    doff[t] = v;
    __syncthreads();
    for (int o = 1; o < 256; o <<= 1){
      int tv = (t >= o) ? doff[t - o] : 0;
      __syncthreads();
      doff[t] += tv;
      __syncthreads();
    }
    int excl = doff[t] - v;
    __syncthreads();
    doff[t] = excl;
    __syncthreads();
    int node = (b << 8) + t;
    if (node < N) offs[node] = beg + doff[t];
    if (b == 0 && t == 0) offs[N] = Etot;
    dcnt[t] = 0;
    __syncthreads();
    for (int i = t; i < cnt; i += 256){
      unsigned pr = pb[i];
      int l = (pr >> 16) & 255;
      int pos = beg + doff[l] + atomicAdd(&dcnt[l], 1);
      csr[pos] = (unsigned short)(pr & 0xFFFF);
    }
    return;
  }

  // ---------- logits_from_x ----------
  int idx = (blockIdx.x - nbuck) * 256 + t;
  int node = idx >> 3, q = idx & 7;
  if (node >= N) return;
  const float* xr = x + (size_t)node * 32;
  float v = 0.f;
  #pragma unroll 8
  for (int k = 0; k < 32; k++) v += xr[k] * Psd[k * 8 + q];
  if (q < 4){
    s_log[node * 4 + q] = v;
    __half2 h0 = __floats2half2_rn(xr[q*8+0], xr[q*8+1]);
    __half2 h1 = __floats2half2_rn(xr[q*8+2], xr[q*8+3]);
    __half2 h2 = __floats2half2_rn(xr[q*8+4], xr[q*8+5]);
    __half2 h3 = __floats2half2_rn(xr[q*8+6], xr[q*8+7]);
    uint4 u;
    u.x = *reinterpret_cast<const unsigned*>(&h0);
    u.y = *reinterpret_cast<const unsigned*>(&h1);
    u.z = *reinterpret_cast<const unsigned*>(&h2);
    u.w = *reinterpret_cast<const unsigned*>(&h3);
    *reinterpret_cast<uint4*>(xh0 + (size_t)node * 32 + q * 8) = u;
  } else {
    d_log[node * 4 + (q - 4)] = v;
  }
}

// ================= fused layer: aggregate (LDS z) + MFMA transform =================
template<int F, int ZW>
__global__ __launch_bounds__(512)
void gat_layer_fused(const __half* __restrict__ xin, const float* __restrict__ s_in,
                     const float* __restrict__ d_in_, const int* __restrict__ off,
                     const unsigned short* __restrict__ csr,
                     const __half* __restrict__ Wpk, const float* __restrict__ cb,
                     const __half* __restrict__ Ppk,
                     __half* __restrict__ xo, float* __restrict__ s_out,
                     float* __restrict__ d_out_, int N)
{
  constexpr int ZP = ZW + 8;
  __shared__ float4 qa[8][2][32];
  __shared__ int    qs[8][2][32];
  __shared__ __half z_lds[16][ZP];
  __shared__ float  outs[16][68];
  __shared__ float  cbs[64];
  const int tid  = threadIdx.x;
  const int wv   = tid >> 6;
  const int lane = tid & 63;
  const int half = lane >> 5;
  const int l32  = lane & 31;
  const int n0 = blockIdx.x * 16;
  const int n = n0 + wv * 2 + half;
  const bool valid = n < N;
  if (tid < 64) cbs[tid] = cb[tid];

  int beg = 0, deg = 0;
  if (valid){ beg = off[n]; deg = off[n + 1] - beg; }

  float d4[4] = {0.f, 0.f, 0.f, 0.f};
  if (valid){
    float4 d4v = reinterpret_cast<const float4*>(d_in_)[n];
    d4[0] = d4v.x; d4[1] = d4v.y; d4[2] = d4v.z; d4[3] = d4v.w;
  }

  float den[4], ex[4];
  int s = 0;
  {
    const bool act = valid && (l32 < deg);
    if (act){
      s = csr[beg + l32];
      float4 sl = reinterpret_cast<const float4*>(s_in)[s];
      float t[4] = {sl.x, sl.y, sl.z, sl.w};
      #pragma unroll
      for (int i = 0; i < 4; i++){
        float u = t[i] + d4[i]; u = (u >= 0.f) ? u : NEG * u;
        ex[i] = __expf(u);
      }
    } else {
      #pragma unroll
      for (int i = 0; i < 4; i++) ex[i] = 0.f;
    }
    #pragma unroll
    for (int i = 0; i < 4; i++) den[i] = wsum32(ex[i]);
  }
  for (int base = 32; base < deg; base += 32){
    const int k = base + l32;
    float e2[4] = {0.f, 0.f, 0.f, 0.f};
    if (k < deg){
      int s2 = csr[beg + k];
      float4 sl = reinterpret_cast<const float4*>(s_in)[s2];
      float t[4] = {sl.x, sl.y, sl.z, sl.w};
      #pragma unroll
      for (int i = 0; i < 4; i++){
        float u = t[i] + d4[i]; u = (u >= 0.f) ? u : NEG * u;
        e2[i] = __expf(u);
      }
    }
    #pragma unroll
    for (int i = 0; i < 4; i++) den[i] += wsum32(e2[i]);
  }

  float dninv[4];
  #pragma unroll
  for (int i = 0; i < 4; i++) dninv[i] = 1.f / fmaxf(den[i], 1e-16f);

  float a0[4] = {0.f,0.f,0.f,0.f};
  float a1[4] = {0.f,0.f,0.f,0.f};
  const float4* qap = qa[wv][half];
  const int*    qsp = qs[wv][half];

  auto accum = [&](int cnt){
    int cntR = (cnt + 3) & ~3;
    if (F == 64){
      const __half* xb = xin + 2 * l32;
      for (int e0 = 0; e0 < cntR; e0 += 4){
        float4 al[4]; int sv[4]; unsigned uv[4];
        #pragma unroll
        for (int j = 0; j < 4; j++){ al[j] = qap[e0 + j]; sv[j] = qsp[e0 + j]; }
        #pragma unroll
        for (int j = 0; j < 4; j++)
          uv[j] = *reinterpret_cast<const unsigned*>(xb + sv[j] * 64);
        #pragma unroll
        for (int j = 0; j < 4; j++){
          float2 f = __half22float2(*reinterpret_cast<const __half2*>(&uv[j]));
          a0[0] += al[j].x * f.x; a1[0] += al[j].x * f.y;
          a0[1] += al[j].y * f.x; a1[1] += al[j].y * f.y;
          a0[2] += al[j].z * f.x; a1[2] += al[j].z * f.y;
          a0[3] += al[j].w * f.x; a1[3] += al[j].w * f.y;
        }
      }
    } else {
      const __half* xb = xin + l32;
      for (int e0 = 0; e0 < cntR; e0 += 4){
        float4 al[4]; int sv[4]; __half hv[4];
        #pragma unroll
        for (int j = 0; j < 4; j++){ al[j] = qap[e0 + j]; sv[j] = qsp[e0 + j]; }
        #pragma unroll
        for (int j = 0; j < 4; j++)
          hv[j] = xb[sv[j] * 32];
        #pragma unroll
        for (int j = 0; j < 4; j++){
          float xv = __half2float(hv[j]);
          a0[0] += al[j].x * xv;
          a0[1] += al[j].y * xv;
          a0[2] += al[j].z * xv;
          a0[3] += al[j].w * xv;
        }
      }
    }
  };

  if (deg <= 32){
    qa[wv][half][l32] = make_float4(ex[0] * dninv[0], ex[1] * dninv[1],
                                    ex[2] * dninv[2], ex[3] * dninv[3]);
    qs[wv][half][l32] = s;
    WAVE_SYNC();
    accum(deg);
  } else {
    for (int base = 0; base < deg; base += 32){
      const int k = base + l32;
      int s2 = 0; float al[4] = {0.f, 0.f, 0.f, 0.f};
      if (k < deg){
        s2 = csr[beg + k];
        float4 sl = reinterpret_cast<const float4*>(s_in)[s2];
        float t[4] = {sl.x, sl.y, sl.z, sl.w};
        #pragma unroll
        for (int i = 0; i < 4; i++){
          float u = t[i] + d4[i]; u = (u >= 0.f) ? u : NEG * u;
          al[i] = __expf(u) * dninv[i];
        }
      }
      qa[wv][half][l32] = make_float4(al[0], al[1], al[2], al[3]);
      qs[wv][half][l32] = s2;
      WAVE_SYNC();
      accum(min(32, deg - base));
      WAVE_SYNC();
    }
  }

  {
    const int r = wv * 2 + half;
    if (F == 64){
      #pragma unroll
      for (int h = 0; h < 4; h++){
        __half2 hv = __floats2half2_rn(a0[h], a1[h]);
        *reinterpret_cast<unsigned*>(&z_lds[r][h * 64 + 2 * l32]) =
            *reinterpret_cast<const unsigned*>(&hv);
      }
    } else {
      #pragma unroll
      for (int h = 0; h < 4; h++)
        z_lds[r][h * 32 + l32] = __float2half(a0[h]);
    }
  }
  __syncthreads();

  const int row = lane & 15, kg = lane >> 4;
  if (wv < 4){
    const int nt = wv;
    f32x4 acc = {0.f,0.f,0.f,0.f};
    const f16x8* wp = reinterpret_cast<const f16x8*>(Wpk) + lane;
    #pragma unroll
    for (int ks = 0; ks < ZW / 32; ks++){
      f16x8 af = *reinterpret_cast<const f16x8*>(&z_lds[row][kg * 8 + ks * 32]);
      acc = __builtin_amdgcn_mfma_f32_16x16x32_f16(af, wp[(ks*4+nt)*64], acc, 0,0,0);
    }
    #pragma unroll
    for (int r = 0; r < 4; r++){
      int rr = kg * 4 + r;
      outs[rr][nt * 16 + row] = fmaxf(acc[r] + cbs[nt * 16 + row], 0.f);
    }
  }
  __syncthreads();

  if (tid < 256){
    int nn = tid >> 4, part = tid & 15;
    int node = n0 + nn;
    if (node < N){
      const float* o = &outs[nn][part * 4];
      __half2 h0 = __floats2half2_rn(o[0], o[1]);
      __half2 h1 = __floats2half2_rn(o[2], o[3]);
      uint2 u;
      u.x = *reinterpret_cast<const unsigned*>(&h0);
      u.y = *reinterpret_cast<const unsigned*>(&h1);
      *reinterpret_cast<uint2*>(xo + (size_t)node * 64 + part * 4) = u;
    }
  }

  if (wv == 4){
    f32x4 lacc = {0.f,0.f,0.f,0.f};
    const f16x8* pp = reinterpret_cast<const f16x8*>(Ppk) + lane;
    #pragma unroll
    for (int ks = 0; ks < 2; ks++){
      f16x8 af;
      #pragma unroll
      for (int j = 0; j < 8; j++) af[j] = (_Float16)outs[row][ks * 32 + kg * 8 + j];
      lacc = __builtin_amdgcn_mfma_f32_16x16x32_f16(af, pp[ks * 64], lacc, 0,0,0);
    }
    if (row < 8){
      float* dst = (row < 4) ? s_out : d_out_;
      int q = row & 3;
      #pragma unroll
      for (int r = 0; r < 4; r++){
        int node = n0 + kg * 4 + r;
        if (node < N) dst[node * 4 + q] = lacc[r];
      }
    }
  }
}

// ---------------- layer-3 aggregation (z to global, 256-wide) ----------------
template<int F>
__global__ __launch_bounds__(256)
void gat_aggregate_z(const __half* __restrict__ xin, const float* __restrict__ s_log,
                     const float* __restrict__ d_log, const int* __restrict__ off,
                     const unsigned short* __restrict__ csr, __half* __restrict__ z, int N)
{
  __shared__ float4 qa[4][2][32];
  __shared__ int    qs[4][2][32];
  const int wv   = threadIdx.x >> 6;
  const int lane = threadIdx.x & 63;
  const int half = lane >> 5;
  const int l32  = lane & 31;
  const int n = blockIdx.x * 8 + wv * 2 + half;
  const bool valid = n < N;

  int beg = 0, deg = 0;
  if (valid){ beg = off[n]; deg = off[n + 1] - beg; }

  float d4[4] = {0.f, 0.f, 0.f, 0.f};
  if (valid){
    float4 d4v = reinterpret_cast<const float4*>(d_log)[n];
    d4[0] = d4v.x; d4[1] = d4v.y; d4[2] = d4v.z; d4[3] = d4v.w;
  }

  float den[4], ex[4];
  int s = 0;
  {
    const bool act = valid && (l32 < deg);
    if (act){
      s = csr[beg + l32];
      float4 sl = reinterpret_cast<const float4*>(s_log)[s];
      float t[4] = {sl.x, sl.y, sl.z, sl.w};
      #pragma unroll
      for (int i = 0; i < 4; i++){
        float u = t[i] + d4[i]; u = (u >= 0.f) ? u : NEG * u;
        ex[i] = __expf(u);
      }
    } else {
      #pragma unroll
      for (int i = 0; i < 4; i++) ex[i] = 0.f;
    }
    #pragma unroll
    for (int i = 0; i < 4; i++) den[i] = wsum32(ex[i]);
  }
  for (int base = 32; base < deg; base += 32){
    const int k = base + l32;
    float e2[4] = {0.f, 0.f, 0.f, 0.f};
    if (k < deg){
      int s2 = csr[beg + k];
      float4 sl = reinterpret_cast<const float4*>(s_log)[s2];
      float t[4] = {sl.x, sl.y, sl.z, sl.w};
      #pragma unroll
      for (int i = 0; i < 4; i++){
        float u = t[i] + d4[i]; u = (u >= 0.f) ? u : NEG * u;
        e2[i] = __expf(u);
      }
    }
    #pragma unroll
    for (int i = 0; i < 4; i++) den[i] += wsum32(e2[i]);
  }

  float dninv[4];
  #pragma unroll
  for (int i = 0; i < 4; i++) dninv[i] = 1.f / fmaxf(den[i], 1e-16f);

  float a0[4] = {0.f,0.f,0.f,0.f};
  float a1[4] = {0.f,0.f,0.f,0.f};
  const float4* qap = qa[wv][half];
  const int*    qsp = qs[wv][half];

  auto accum = [&](int cnt){
    int cntR = (cnt + 3) & ~3;
    const __half* xb = xin + 2 * l32;
    for (int e0 = 0; e0 < cntR; e0 += 4){
      float4 al[4]; int sv[4]; unsigned uv[4];
      #pragma unroll
      for (int j = 0; j < 4; j++){ al[j] = qap[e0 + j]; sv[j] = qsp[e0 + j]; }
      #pragma unroll
      for (int j = 0; j < 4; j++)
        uv[j] = *reinterpret_cast<const unsigned*>(xb + sv[j] * 64);
      #pragma unroll
      for (int j = 0; j < 4; j++){
        float2 f = __half22float2(*reinterpret_cast<const __half2*>(&uv[j]));
        a0[0] += al[j].x * f.x; a1[0] += al[j].x * f.y;
        a0[1] += al[j].y * f.x; a1[1] += al[j].y * f.y;
        a0[2] += al[j].z * f.x; a1[2] += al[j].z * f.y;
        a0[3] += al[j].w * f.x; a1[3] += al[j].w * f.y;
      }
    }
  };

  if (deg <= 32){
    qa[wv][half][l32] = make_float4(ex[0] * dninv[0], ex[1] * dninv[1],
                                    ex[2] * dninv[2], ex[3] * dninv[3]);
    qs[wv][half][l32] = s;
    WAVE_SYNC();
    accum(deg);
  } else {
    for (int base = 0; base < deg; base += 32){
      const int k = base + l32;
      int s2 = 0; float al[4] = {0.f, 0.f, 0.f, 0.f};
      if (k < deg){
        s2 = csr[beg + k];
        float4 sl = reinterpret_cast<const float4*>(s_log)[s2];
        float t[4] = {sl.x, sl.y, sl.z, sl.w};
        #pragma unroll
        for (int i = 0; i < 4; i++){
          float u = t[i] + d4[i]; u = (u >= 0.f) ? u : NEG * u;
          al[i] = __expf(u) * dninv[i];
        }
      }
      qa[wv][half][l32] = make_float4(al[0], al[1], al[2], al[3]);
      qs[wv][half][l32] = s2;
      WAVE_SYNC();
      accum(min(32, deg - base));
      WAVE_SYNC();
    }
  }

  if (valid){
    const size_t zb = (size_t)n * 256 + 2 * l32;
    #pragma unroll
    for (int h = 0; h < 4; h++){
      __half2 hv = __floats2half2_rn(a0[h], a1[h]);
      *reinterpret_cast<unsigned*>(z + zb + h * 64) =
          *reinterpret_cast<const unsigned*>(&hv);
    }
  }
}

// ---------------- pooling (4-way split) + MLP head ----------------
__global__ __launch_bounds__(256)
void pool_partial(const __half* __restrict__ z3, const int* __restrict__ bnd,
                  float* __restrict__ psum)
{
  const int blk = blockIdx.x, tid = threadIdx.x;
  const int g = blk >> 2, part = blk & 3;
  const int s = bnd[g], e = bnd[g + 1];
  const int cp = tid & 127, rp = tid >> 7;
  float ax = 0.f, ay = 0.f;
  for (int n = s + part + 4 * rp; n < e; n += 8){
    __half2 hv = *reinterpret_cast<const __half2*>(z3 + (size_t)n * 256 + 2 * cp);
    float2 f = __half22float2(hv);
    ax += f.x; ay += f.y;
  }
  __shared__ float shx[2][128], shy[2][128];
  shx[rp][cp] = ax; shy[rp][cp] = ay;
  __syncthreads();
  if (tid < 128){
    psum[(size_t)blk * 256 + 2 * tid]     = shx[0][tid] + shx[1][tid];
    psum[(size_t)blk * 256 + 2 * tid + 1] = shy[0][tid] + shy[1][tid];
  }
}

__global__ __launch_bounds__(256)
void head_mlp(const float* __restrict__ psum, const int* __restrict__ bnd,
              const float* __restrict__ Wcp3, const float* __restrict__ cb3,
              const float* __restrict__ m1w, const float* __restrict__ m1b,
              const float* __restrict__ m2w, const float* __restrict__ m2b,
              float* __restrict__ out)
{
  const int g = blockIdx.x, tid = threadIdx.x;
  const float cnt = (float)max(bnd[g + 1] - bnd[g], 1);
  __shared__ float zbar[256];
  const float* pb = psum + (size_t)g * 1024;
  zbar[tid] = (pb[tid] + pb[256 + tid] + pb[512 + tid] + pb[768 + tid]) / cnt;
  __syncthreads();
  const int c = tid & 63, part = tid >> 6;
  float tp = 0.f;
  #pragma unroll 8
  for (int k = part * 64; k < part * 64 + 64; k++) tp += zbar[k] * Wcp3[k * 64 + c];
  __shared__ float tsh[4][64];
  tsh[part][c] = tp;
  __syncthreads();
  __shared__ float tvec[64];
  if (tid < 64)
    tvec[tid] = tsh[0][tid] + tsh[1][tid] + tsh[2][tid] + tsh[3][tid] + cb3[tid];
  __syncthreads();
  float a = m1b[tid];
  #pragma unroll 8
  for (int cc = 0; cc < 64; cc++) a += tvec[cc] * m1w[cc * 256 + tid];
  __shared__ float g1row[256];
  g1row[tid] = fmaxf(a, 0.f);
  __syncthreads();
  float o = m2b[tid];
  #pragma unroll 8
  for (int k = 0; k < 256; k++) o += g1row[k] * m2w[k * 256 + tid];
  out[g * 256 + tid] = o;
}

// ---------------- launcher ----------------
extern "C" void kernel_launch(void* const* d_in, const int* in_sizes, int n_in,
                              void* d_out, int out_size, void* d_ws, size_t ws_size,
                              hipStream_t stream)
{
  const float* x     = (const float*)d_in[0];
  const int*   ei    = (const int*)d_in[1];
  const int*   batch = (const int*)d_in[2];
  const float* W1  = (const float*)d_in[4];
  const float* a1s = (const float*)d_in[5];
  const float* a1d = (const float*)d_in[6];
  const float* b1  = (const float*)d_in[7];
  const float* h1w = (const float*)d_in[8];
  const float* h1b = (const float*)d_in[9];
  const float* W2  = (const float*)d_in[10];
  const float* a2s = (const float*)d_in[11];
  const float* a2d = (const float*)d_in[12];
  const float* b2  = (const float*)d_in[13];
  const float* h2w = (const float*)d_in[14];
  const float* h2b = (const float*)d_in[15];
  const float* W3  = (const float*)d_in[16];
  const float* a3s = (const float*)d_in[17];
  const float* a3d = (const float*)d_in[18];
  const float* b3  = (const float*)d_in[19];
  const float* h3w = (const float*)d_in[20];
  const float* h3b = (const float*)d_in[21];
  const float* m1w = (const float*)d_in[22];
  const float* m1b = (const float*)d_in[23];
  const float* m2w = (const float*)d_in[24];
  const float* m2b = (const float*)d_in[25];

  const int N = in_sizes[0] / 32;
  const int E = in_sizes[1] / 2;
  const int G = out_size / 256;
  const int Etot = E + N;
  const int nbuck = (N + 255) >> 8;

  char* p = (char*)d_ws;
  auto alloc = [&](size_t bytes) -> void* {
    void* r = (void*)p;
    p += ((bytes + 255) / 256) * 256;
    return r;
  };
  __half* zbuf   = (__half*)alloc((size_t)N * GHC * 2);
  __half* xh0    = (__half*)alloc((size_t)N * 32 * 2);
  __half* xh1    = (__half*)alloc((size_t)N * CH * 2);
  __half* xh2    = (__half*)alloc((size_t)N * CH * 2);
  float* s_logA  = (float*)alloc((size_t)N * HD * 4);
  float* d_logA  = (float*)alloc((size_t)N * HD * 4);
  float* s_logB  = (float*)alloc((size_t)N * HD * 4);
  float* d_logB  = (float*)alloc((size_t)N * HD * 4);
  int*   offs    = (int*)alloc((size_t)(N + 1) * 4);
  unsigned short* csr = (unsigned short*)alloc((size_t)Etot * 2);
  unsigned* pairs = (unsigned*)alloc((size_t)nbuck * BCAP * 4);
  int*    bres   = (int*)alloc(256 * 4);
  __half* Ppk2   = (__half*)alloc(1024 * 2);
  __half* Ppk3   = (__half*)alloc(1024 * 2);
  int*   bnd     = (int*)alloc((size_t)(G + 1) * 4);
  float* psum    = (float*)alloc((size_t)G * 4 * 256 * 4);
  float* Wcp3    = (float*)alloc(256 * 64 * 4);
  float* Psd1    = (float*)alloc(32 * 8 * 4);
  float* cb1     = (float*)alloc(64 * 4);
  float* cb2     = (float*)alloc(64 * 4);
  float* cb3     = (float*)alloc(64 * 4);
  __half* Wpk1   = (__half*)alloc(128 * 64 * 2);
  __half* Wpk2   = (__half*)alloc(256 * 64 * 2);

  hipMemsetAsync(bres, 0, 5120, stream);   // bres + Ppk2 + Ppk3

  const int cb_blocks = (Etot + CHUNK - 1) / CHUNK;
  const int fuse_blocks = 163 + (G + 256) / 256;
  front_kernel<<<cb_blocks + fuse_blocks, 256, 0, stream>>>(
      ei, E, N, cb_blocks, bres, pairs,
      W1, a1s, a1d, b1, h1w, h1b,
      W2, a2s, a2d, b2, h2w, h2b,
      W3, a3s, a3d, b3, h3w, h3b,
      Wpk1, Psd1, cb1, Wpk2, Ppk2, cb2, Wcp3, Ppk3, cb3,
      batch, G, bnd);

  const int lg_blocks = ((size_t)N * 8 + 255) / 256;
  mid_kernel<<<nbuck + lg_blocks, 256, 0, stream>>>(
      pairs, bres, N, Etot, nbuck, offs, csr,
      x, Psd1, s_logA, d_logA, xh0);

  const int fgrid = (N + 15) / 16;
  gat_layer_fused<32, 128><<<fgrid, 512, 0, stream>>>(xh0, s_logA, d_logA, offs, csr,
                                                      Wpk1, cb1, Ppk2, xh1, s_logB, d_logB, N);
  gat_layer_fused<64, 256><<<fgrid, 512, 0, stream>>>(xh1, s_logB, d_logB, offs, csr,
                                                      Wpk2, cb2, Ppk3, xh2, s_logA, d_logA, N);

  const int ab = (N + 7) / 8;
  gat_aggregate_z<64><<<ab, 256, 0, stream>>>(xh2, s_logA, d_logA, offs, csr, zbuf, N);

  pool_partial<<<G * 4, 256, 0, stream>>>(zbuf, bnd, psum);
  head_mlp<<<G, 256, 0, stream>>>(psum, bnd, Wcp3, cb3, m1w, m1b, m2w, m2b, (float*)d_out);
}